// Round 1
// baseline (1711.630 us; speedup 1.0000x reference)
//
#include <hip/hip_runtime.h>
#include <hip/hip_fp16.h>
#include <float.h>
#include <math.h>

#define D_IN 32
#define D_MAIN 128
#define D_BLOCK 256
#define CTX 96
#define LN_EPS 1e-5f
#define ENC_ROWS 16

// ---------------------------------------------------------------------------
// Encoder: h = x@lin_W+b ; h += relu(h@W1+b1)@W2+b2 ; h += relu(LN(h)@W1+b1)@W2+b2
//          k = LN(h)@K_W + K_b ; optional knorm and h output.
// One block = ENC_ROWS rows, 256 threads, all activations in LDS.
// ---------------------------------------------------------------------------

__device__ __forceinline__ void enc_mlp_a(float src[ENC_ROWS][D_MAIN],
                                          float dst[ENC_ROWS][D_BLOCK],
                                          const float* __restrict__ W1,
                                          const float* __restrict__ b1, int t)
{
  float a[ENC_ROWS];
#pragma unroll
  for (int r = 0; r < ENC_ROWS; ++r) a[r] = 0.f;
  for (int kk = 0; kk < D_MAIN; kk += 4) {
    const float w0 = W1[(kk + 0) * D_BLOCK + t];
    const float w1 = W1[(kk + 1) * D_BLOCK + t];
    const float w2 = W1[(kk + 2) * D_BLOCK + t];
    const float w3 = W1[(kk + 3) * D_BLOCK + t];
#pragma unroll
    for (int r = 0; r < ENC_ROWS; ++r) {
      const float4 h4 = *(const float4*)&src[r][kk];
      a[r] += h4.x * w0 + h4.y * w1 + h4.z * w2 + h4.w * w3;
    }
  }
  const float bb = b1[t];
#pragma unroll
  for (int r = 0; r < ENC_ROWS; ++r) dst[r][t] = fmaxf(a[r] + bb, 0.f);
}

__device__ __forceinline__ void enc_mlp_b(float src[ENC_ROWS][D_BLOCK],
                                          float dst[ENC_ROWS][D_MAIN],
                                          const float* __restrict__ W2,
                                          const float* __restrict__ b2, int t)
{
  const int c = t & (D_MAIN - 1);
  const int rg = (t >> 7) * (ENC_ROWS / 2);
  float a[ENC_ROWS / 2];
#pragma unroll
  for (int i = 0; i < ENC_ROWS / 2; ++i) a[i] = 0.f;
  for (int kk = 0; kk < D_BLOCK; kk += 4) {
    const float w0 = W2[(kk + 0) * D_MAIN + c];
    const float w1 = W2[(kk + 1) * D_MAIN + c];
    const float w2_ = W2[(kk + 2) * D_MAIN + c];
    const float w3 = W2[(kk + 3) * D_MAIN + c];
#pragma unroll
    for (int i = 0; i < ENC_ROWS / 2; ++i) {
      const float4 u4 = *(const float4*)&src[rg + i][kk];
      a[i] += u4.x * w0 + u4.y * w1 + u4.z * w2_ + u4.w * w3;
    }
  }
  const float bb = b2[c];
#pragma unroll
  for (int i = 0; i < ENC_ROWS / 2; ++i) dst[rg + i][c] += a[i] + bb;
}

__device__ __forceinline__ void enc_ln(float hs[ENC_ROWS][D_MAIN],
                                       float hn[ENC_ROWS][D_MAIN],
                                       const float* __restrict__ g,
                                       const float* __restrict__ bvec,
                                       float* s_mu, float* s_rs, int t)
{
  if (t < ENC_ROWS) {
    float s = 0.f, ss = 0.f;
    for (int c = 0; c < D_MAIN; ++c) {
      const float v = hs[t][c];
      s += v; ss += v * v;
    }
    const float mu = s * (1.f / D_MAIN);
    const float var = ss * (1.f / D_MAIN) - mu * mu;
    s_mu[t] = mu;
    s_rs[t] = rsqrtf(var + LN_EPS);
  }
  __syncthreads();
  const int c = t & (D_MAIN - 1);
  const int rg = (t >> 7) * (ENC_ROWS / 2);
  const float gg = g[c], bb = bvec[c];
#pragma unroll
  for (int i = 0; i < ENC_ROWS / 2; ++i) {
    const int r = rg + i;
    hn[r][c] = (hs[r][c] - s_mu[r]) * s_rs[r] * gg + bb;
  }
  __syncthreads();
}

__global__ __launch_bounds__(256) void encode_kernel(
    const float* __restrict__ xin, int nrows,
    const float* __restrict__ lin_W, const float* __restrict__ lin_b,
    const float* __restrict__ e0_W1, const float* __restrict__ e0_b1,
    const float* __restrict__ e0_W2, const float* __restrict__ e0_b2,
    const float* __restrict__ e1_g, const float* __restrict__ e1_b,
    const float* __restrict__ e1_W1, const float* __restrict__ e1_b1,
    const float* __restrict__ e1_W2, const float* __restrict__ e1_b2,
    const float* __restrict__ mix_g, const float* __restrict__ mix_b,
    const float* __restrict__ K_W, const float* __restrict__ K_b,
    float* __restrict__ k_out, float* __restrict__ knorm_out,
    float* __restrict__ h_out)
{
  __shared__ float xs[ENC_ROWS][D_IN];
  __shared__ float hs[ENC_ROWS][D_MAIN];
  __shared__ float hn[ENC_ROWS][D_MAIN];
  __shared__ float bs[ENC_ROWS][D_BLOCK];
  __shared__ float s_mu[ENC_ROWS], s_rs[ENC_ROWS];
  const int t = threadIdx.x;
  const int row0 = blockIdx.x * ENC_ROWS;

  for (int i = t; i < ENC_ROWS * D_IN; i += 256) {
    const int r = i >> 5, c = i & 31;
    const int gr = row0 + r;
    xs[r][c] = (gr < nrows) ? xin[(size_t)gr * D_IN + c] : 0.f;
  }
  __syncthreads();
  // input linear
  {
    const int c = t & (D_MAIN - 1);
    const int rg = (t >> 7) * (ENC_ROWS / 2);
    float a[ENC_ROWS / 2];
#pragma unroll
    for (int i = 0; i < ENC_ROWS / 2; ++i) a[i] = 0.f;
    for (int kk = 0; kk < D_IN; ++kk) {
      const float w = lin_W[kk * D_MAIN + c];
#pragma unroll
      for (int i = 0; i < ENC_ROWS / 2; ++i) a[i] += xs[rg + i][kk] * w;
    }
    const float bb = lin_b[c];
#pragma unroll
    for (int i = 0; i < ENC_ROWS / 2; ++i) hs[rg + i][c] = a[i] + bb;
  }
  __syncthreads();
  // block 0 (no prenorm)
  enc_mlp_a(hs, bs, e0_W1, e0_b1, t);
  __syncthreads();
  enc_mlp_b(bs, hs, e0_W2, e0_b2, t);
  __syncthreads();
  // block 1 (prenorm)
  enc_ln(hs, hn, e1_g, e1_b, s_mu, s_rs, t);
  enc_mlp_a(hn, bs, e1_W1, e1_b1, t);
  __syncthreads();
  enc_mlp_b(bs, hs, e1_W2, e1_b2, t);
  __syncthreads();
  // mixer LN + K projection
  enc_ln(hs, hn, mix_g, mix_b, s_mu, s_rs, t);
  {
    const int c = t & (D_MAIN - 1);
    const int rg = (t >> 7) * (ENC_ROWS / 2);
    float a[ENC_ROWS / 2];
#pragma unroll
    for (int i = 0; i < ENC_ROWS / 2; ++i) a[i] = 0.f;
    for (int kk = 0; kk < D_MAIN; kk += 4) {
      const float w0 = K_W[(kk + 0) * D_MAIN + c];
      const float w1 = K_W[(kk + 1) * D_MAIN + c];
      const float w2 = K_W[(kk + 2) * D_MAIN + c];
      const float w3 = K_W[(kk + 3) * D_MAIN + c];
#pragma unroll
      for (int i = 0; i < ENC_ROWS / 2; ++i) {
        const float4 h4 = *(const float4*)&hn[rg + i][kk];
        a[i] += h4.x * w0 + h4.y * w1 + h4.z * w2 + h4.w * w3;
      }
    }
    const float bb = K_b[c];
#pragma unroll
    for (int i = 0; i < ENC_ROWS / 2; ++i) {
      const int gr = row0 + rg + i;
      const float kv = a[i] + bb;
      bs[rg + i][c] = kv;
      if (gr < nrows) k_out[(size_t)gr * D_MAIN + c] = kv;
    }
    if (h_out) {
#pragma unroll
      for (int i = 0; i < ENC_ROWS / 2; ++i) {
        const int gr = row0 + rg + i;
        if (gr < nrows) h_out[(size_t)gr * D_MAIN + c] = hs[rg + i][c];
      }
    }
  }
  __syncthreads();
  if (knorm_out && t < ENC_ROWS) {
    const int gr = row0 + t;
    if (gr < nrows) {
      float s = 0.f;
      for (int c = 0; c < D_MAIN; ++c) {
        const float v = bs[t][c];
        s += v * v;
      }
      knorm_out[gr] = s;
    }
  }
}

// ---------------------------------------------------------------------------
// Score kernel: S[b][j] = 2*dot(xk[b], ck[j]) - ||ck[j]||^2  (fp16 storage)
// selection by largest S == smallest squared distance.
// ---------------------------------------------------------------------------
#define SC_BR 64
#define SC_BJ 32
#define SC_PAD 132

__global__ __launch_bounds__(256) void score_kernel(
    const float* __restrict__ xk, const float* __restrict__ ck,
    const float* __restrict__ cknorm, int N, int Npad, int B,
    __half* __restrict__ S)
{
  __shared__ float ks[SC_BR * SC_PAD];
  __shared__ float cs[SC_BJ * SC_PAD];
  __shared__ float cn[SC_BJ];
  const int t = threadIdx.x;
  const int j0 = blockIdx.x * SC_BJ;
  const int b0 = blockIdx.y * SC_BR;

  for (int i = t; i < SC_BR * (D_MAIN / 4); i += 256) {
    const int r = i >> 5, c4 = (i & 31) * 4;
    const int bg = b0 + r;
    float4 v = make_float4(0.f, 0.f, 0.f, 0.f);
    if (bg < B) v = *(const float4*)&xk[(size_t)bg * D_MAIN + c4];
    *(float4*)&ks[r * SC_PAD + c4] = v;
  }
  for (int i = t; i < SC_BJ * (D_MAIN / 4); i += 256) {
    const int r = i >> 5, c4 = (i & 31) * 4;
    const int j = j0 + r;
    float4 v = make_float4(0.f, 0.f, 0.f, 0.f);
    if (j < N) v = *(const float4*)&ck[(size_t)j * D_MAIN + c4];
    *(float4*)&cs[r * SC_PAD + c4] = v;
  }
  if (t < SC_BJ) cn[t] = (j0 + t < N) ? cknorm[j0 + t] : 0.f;
  __syncthreads();

  const int tj = t & 15, tb = t >> 4;
  float acc[4][2];
#pragma unroll
  for (int ib = 0; ib < 4; ++ib)
#pragma unroll
    for (int ij = 0; ij < 2; ++ij) acc[ib][ij] = 0.f;

  for (int c = 0; c < D_MAIN; c += 4) {
    float4 kf[4], cf[2];
#pragma unroll
    for (int ib = 0; ib < 4; ++ib)
      kf[ib] = *(const float4*)&ks[(tb + 16 * ib) * SC_PAD + c];
#pragma unroll
    for (int ij = 0; ij < 2; ++ij)
      cf[ij] = *(const float4*)&cs[(tj + 16 * ij) * SC_PAD + c];
#pragma unroll
    for (int ib = 0; ib < 4; ++ib)
#pragma unroll
      for (int ij = 0; ij < 2; ++ij)
        acc[ib][ij] += kf[ib].x * cf[ij].x + kf[ib].y * cf[ij].y +
                       kf[ib].z * cf[ij].z + kf[ib].w * cf[ij].w;
  }
#pragma unroll
  for (int ib = 0; ib < 4; ++ib) {
#pragma unroll
    for (int ij = 0; ij < 2; ++ij) {
      const int bl = tb + 16 * ib, jl = tj + 16 * ij;
      const int bg = b0 + bl, j = j0 + jl;
      if (bg < B) {
        const float sv = (j < N) ? (2.f * acc[ib][ij] - cn[jl]) : -65504.f;
        S[(size_t)bg * Npad + j] = __float2half(sv);
      }
    }
  }
}

// ---------------------------------------------------------------------------
// Top-K per row: 2-level histogram threshold -> collect -> bitonic sort.
// ---------------------------------------------------------------------------
#define TK_BINS 1024
#define TK_CAP 2048

__global__ __launch_bounds__(256) void topk_kernel(
    const __half* __restrict__ S, int N, int Npad, int* __restrict__ idx_out)
{
  __shared__ int hist[TK_BINS];
  __shared__ float sbuf[TK_CAP];
  __shared__ int ibuf[TK_CAP];
  __shared__ float red[256];
  __shared__ float s_mn, s_inv1, s_lo1, s_inv2;
  __shared__ int s_B1, s_B2, s_cab, s_count;
  const int t = threadIdx.x;
  const int b = blockIdx.x;
  const __half* row = S + (size_t)b * Npad;

  float mn = FLT_MAX, mx = -FLT_MAX;
  for (int j = t; j < N; j += 256) {
    const float v = __half2float(row[j]);
    mn = fminf(mn, v);
    mx = fmaxf(mx, v);
  }
  red[t] = mx;
  __syncthreads();
  for (int o = 128; o > 0; o >>= 1) {
    if (t < o) red[t] = fmaxf(red[t], red[t + o]);
    __syncthreads();
  }
  const float gmx = red[0];
  __syncthreads();
  red[t] = mn;
  __syncthreads();
  for (int o = 128; o > 0; o >>= 1) {
    if (t < o) red[t] = fminf(red[t], red[t + o]);
    __syncthreads();
  }
  if (t == 0) {
    s_mn = red[0];
    const float range = fmaxf(gmx - red[0], 1e-20f);
    s_inv1 = (float)TK_BINS / range;
  }
  __syncthreads();
  const float bmn = s_mn, inv1 = s_inv1;

  for (int i = t; i < TK_BINS; i += 256) hist[i] = 0;
  __syncthreads();
  for (int j = t; j < N; j += 256) {
    const float v = __half2float(row[j]);
    int bin = (int)((v - bmn) * inv1);
    bin = min(max(bin, 0), TK_BINS - 1);
    atomicAdd(&hist[bin], 1);
  }
  __syncthreads();
  if (t == 0) {
    int c = 0, B1 = 0;
    for (int q = TK_BINS - 1; q >= 0; --q) {
      c += hist[q];
      if (c >= CTX) { B1 = q; break; }
    }
    s_B1 = B1;
    s_cab = c - hist[B1];
    s_lo1 = bmn + (float)B1 / inv1;
    s_inv2 = inv1 * (float)TK_BINS;
  }
  __syncthreads();
  const int B1 = s_B1;
  const float lo1 = s_lo1, inv2 = s_inv2;

  for (int i = t; i < TK_BINS; i += 256) hist[i] = 0;
  __syncthreads();
  for (int j = t; j < N; j += 256) {
    const float v = __half2float(row[j]);
    int bin = (int)((v - bmn) * inv1);
    bin = min(max(bin, 0), TK_BINS - 1);
    if (bin == B1) {
      int b2 = (int)((v - lo1) * inv2);
      b2 = min(max(b2, 0), TK_BINS - 1);
      atomicAdd(&hist[b2], 1);
    }
  }
  __syncthreads();
  if (t == 0) {
    int c = s_cab, B2 = 0;
    for (int q = TK_BINS - 1; q >= 0; --q) {
      c += hist[q];
      if (c >= CTX) { B2 = q; break; }
    }
    s_B2 = B2;
    s_count = 0;
  }
  __syncthreads();
  const int B2 = s_B2;

  for (int j = t; j < N; j += 256) {
    const float v = __half2float(row[j]);
    int bin = (int)((v - bmn) * inv1);
    bin = min(max(bin, 0), TK_BINS - 1);
    bool take = (bin > B1);
    if (bin == B1) {
      int b2 = (int)((v - lo1) * inv2);
      b2 = min(max(b2, 0), TK_BINS - 1);
      take = (b2 >= B2);
    }
    if (take) {
      const int pos = atomicAdd(&s_count, 1);
      if (pos < TK_CAP) { sbuf[pos] = v; ibuf[pos] = j; }
    }
  }
  __syncthreads();
  const int m = min(s_count, TK_CAP);
  for (int i = t; i < TK_CAP; i += 256) {
    if (i >= m) { sbuf[i] = -FLT_MAX; ibuf[i] = 0x7FFFFFFF; }
  }
  __syncthreads();
  // bitonic: descending by score, ascending idx tiebreak (deterministic)
  for (int k = 2; k <= TK_CAP; k <<= 1) {
    for (int stride = k >> 1; stride > 0; stride >>= 1) {
      for (int i = t; i < TK_CAP; i += 256) {
        const int ixj = i ^ stride;
        if (ixj > i) {
          const float sa = sbuf[i], sb = sbuf[ixj];
          const int ia = ibuf[i], ib = ibuf[ixj];
          const bool before = (sa > sb) || (sa == sb && ia < ib);
          const bool want = ((i & k) == 0);
          if (before != want) {
            sbuf[i] = sb; sbuf[ixj] = sa;
            ibuf[i] = ib; ibuf[ixj] = ia;
          }
        }
      }
      __syncthreads();
    }
  }
  if (t < CTX) idx_out[b * CTX + t] = ibuf[t];
}

// ---------------------------------------------------------------------------
// Finalize: exact sims + softmax, T-module (4 neighbors/pass), label encoder,
// predictor block, head. One block per query row.
// ---------------------------------------------------------------------------
__global__ __launch_bounds__(256) void finalize_kernel(
    const float* __restrict__ xh, const float* __restrict__ xk,
    const float* __restrict__ ck, const float* __restrict__ cand_y,
    const int* __restrict__ ctx_idx,
    const float* __restrict__ T_W1, const float* __restrict__ T_b1,
    const float* __restrict__ T_W2,
    const float* __restrict__ lab_w, const float* __restrict__ lab_b,
    const float* __restrict__ p0_g, const float* __restrict__ p0_b,
    const float* __restrict__ p0_W1, const float* __restrict__ p0_b1,
    const float* __restrict__ p0_W2, const float* __restrict__ p0_b2,
    const float* __restrict__ head_g, const float* __restrict__ head_b,
    const float* __restrict__ head_W, const float* __restrict__ head_bias,
    float* __restrict__ out)
{
  const int CKP = D_MAIN + 1;
  __shared__ float ckc[CTX * (D_MAIN + 1)];
  __shared__ float kb[D_MAIN], xr[D_MAIN], accv[D_MAIN];
  __shared__ float diffs[4][D_MAIN];
  __shared__ float ubuf[4][D_BLOCK];
  __shared__ float vbuf[4][D_BLOCK];
  __shared__ float probs[CTX], ys[CTX];
  __shared__ int idxs[CTX];
  __shared__ float s_scalar[4];
  const int t = threadIdx.x;
  const int b = blockIdx.x;

  if (t < CTX) {
    const int j = ctx_idx[b * CTX + t];
    idxs[t] = j;
    ys[t] = cand_y[j];
  }
  if (t < D_MAIN) {
    kb[t] = xk[(size_t)b * D_MAIN + t];
    xr[t] = xh[(size_t)b * D_MAIN + t];
    accv[t] = 0.f;
  }
  __syncthreads();
  for (int i = t; i < CTX * D_MAIN; i += 256) {
    const int r = i >> 7, c = i & 127;
    ckc[r * CKP + c] = ck[(size_t)idxs[r] * D_MAIN + c];
  }
  __syncthreads();
  // exact sims = -||k - ck||^2
  if (t < CTX) {
    float s = 0.f;
    for (int c = 0; c < D_MAIN; ++c) {
      const float d = kb[c] - ckc[t * CKP + c];
      s += d * d;
    }
    probs[t] = -s;
  }
  __syncthreads();
  if (t == 0) {
    float mval = -FLT_MAX;
    for (int i = 0; i < CTX; ++i) mval = fmaxf(mval, probs[i]);
    float sum = 0.f;
    for (int i = 0; i < CTX; ++i) {
      const float e = expf(probs[i] - mval);
      probs[i] = e;
      sum += e;
    }
    const float inv = 1.f / sum;
    float sy = 0.f;
    for (int i = 0; i < CTX; ++i) {
      probs[i] *= inv;
      sy += probs[i] * ys[i];
    }
    s_scalar[0] = sy;
  }
  __syncthreads();

  for (int jb = 0; jb < CTX; jb += 4) {
    for (int i = t; i < 4 * D_MAIN; i += 256) {
      const int jj = i >> 7, c = i & 127;
      diffs[jj][c] = kb[c] - ckc[(jb + jj) * CKP + c];
    }
    __syncthreads();
    {
      float u[4] = {0.f, 0.f, 0.f, 0.f};
      for (int c = 0; c < D_MAIN; c += 4) {
        const float w0 = T_W1[(c + 0) * D_BLOCK + t];
        const float w1 = T_W1[(c + 1) * D_BLOCK + t];
        const float w2 = T_W1[(c + 2) * D_BLOCK + t];
        const float w3 = T_W1[(c + 3) * D_BLOCK + t];
#pragma unroll
        for (int jj = 0; jj < 4; ++jj) {
          const float4 d4 = *(const float4*)&diffs[jj][c];
          u[jj] += d4.x * w0 + d4.y * w1 + d4.z * w2 + d4.w * w3;
        }
      }
      const float bb = T_b1[t];
#pragma unroll
      for (int jj = 0; jj < 4; ++jj) ubuf[jj][t] = fmaxf(u[jj] + bb, 0.f);
    }
    __syncthreads();
    {
      const int c = t & 127;
      const int d0 = (t >> 7) * 128;
      float v[4] = {0.f, 0.f, 0.f, 0.f};
      for (int d = d0; d < d0 + 128; d += 4) {
        const float w0 = T_W2[(d + 0) * D_MAIN + c];
        const float w1 = T_W2[(d + 1) * D_MAIN + c];
        const float w2 = T_W2[(d + 2) * D_MAIN + c];
        const float w3 = T_W2[(d + 3) * D_MAIN + c];
#pragma unroll
        for (int jj = 0; jj < 4; ++jj) {
          const float4 u4 = *(const float4*)&ubuf[jj][d];
          v[jj] += u4.x * w0 + u4.y * w1 + u4.z * w2 + u4.w * w3;
        }
      }
#pragma unroll
      for (int jj = 0; jj < 4; ++jj) vbuf[jj][t] = v[jj];
    }
    __syncthreads();
    if (t < D_MAIN) {
      float a = accv[t];
#pragma unroll
      for (int jj = 0; jj < 4; ++jj)
        a += probs[jb + jj] * (vbuf[jj][t] + vbuf[jj][t + 128]);
      accv[t] = a;
    }
    __syncthreads();
  }
  // x = xh + context_x
  if (t < D_MAIN)
    xr[t] = xr[t] + accv[t] + s_scalar[0] * lab_w[t] + lab_b[t];
  __syncthreads();
  // predictor prenorm block
  if (t == 0) {
    float s = 0.f, ss = 0.f;
    for (int c = 0; c < D_MAIN; ++c) { const float v = xr[c]; s += v; ss += v * v; }
    const float mu = s / D_MAIN;
    s_scalar[1] = mu;
    s_scalar[2] = rsqrtf(ss / D_MAIN - mu * mu + LN_EPS);
  }
  __syncthreads();
  if (t < D_MAIN)
    diffs[0][t] = (xr[t] - s_scalar[1]) * s_scalar[2] * p0_g[t] + p0_b[t];
  __syncthreads();
  {
    float u = 0.f;
    for (int c = 0; c < D_MAIN; c += 4) {
      const float w0 = p0_W1[(c + 0) * D_BLOCK + t];
      const float w1 = p0_W1[(c + 1) * D_BLOCK + t];
      const float w2 = p0_W1[(c + 2) * D_BLOCK + t];
      const float w3 = p0_W1[(c + 3) * D_BLOCK + t];
      const float4 d4 = *(const float4*)&diffs[0][c];
      u += d4.x * w0 + d4.y * w1 + d4.z * w2 + d4.w * w3;
    }
    ubuf[0][t] = fmaxf(u + p0_b1[t], 0.f);
  }
  __syncthreads();
  {
    const int c = t & 127;
    const int d0 = (t >> 7) * 128;
    float v = 0.f;
    for (int d = d0; d < d0 + 128; d += 4) {
      const float w0 = p0_W2[(d + 0) * D_MAIN + c];
      const float w1 = p0_W2[(d + 1) * D_MAIN + c];
      const float w2 = p0_W2[(d + 2) * D_MAIN + c];
      const float w3 = p0_W2[(d + 3) * D_MAIN + c];
      const float4 u4 = *(const float4*)&ubuf[0][d];
      v += u4.x * w0 + u4.y * w1 + u4.z * w2 + u4.w * w3;
    }
    vbuf[0][t] = v;
  }
  __syncthreads();
  if (t < D_MAIN) xr[t] += vbuf[0][t] + vbuf[0][t + 128] + p0_b2[t];
  __syncthreads();
  // head: LN -> relu -> linear
  if (t == 0) {
    float s = 0.f, ss = 0.f;
    for (int c = 0; c < D_MAIN; ++c) { const float v = xr[c]; s += v; ss += v * v; }
    const float mu = s / D_MAIN;
    s_scalar[1] = mu;
    s_scalar[2] = rsqrtf(ss / D_MAIN - mu * mu + LN_EPS);
  }
  __syncthreads();
  if (t < D_MAIN) {
    float hv = (xr[t] - s_scalar[1]) * s_scalar[2] * head_g[t] + head_b[t];
    hv = fmaxf(hv, 0.f);
    diffs[0][t] = hv * head_W[t];
  }
  __syncthreads();
  if (t == 0) {
    float s = 0.f;
    for (int c = 0; c < D_MAIN; ++c) s += diffs[0][c];
    out[b] = s + head_bias[0];
  }
}

// ---------------------------------------------------------------------------
extern "C" void kernel_launch(void* const* d_in, const int* in_sizes, int n_in,
                              void* d_out, int out_size, void* d_ws, size_t ws_size,
                              hipStream_t stream)
{
  const float* x_num   = (const float*)d_in[0];
  const float* cand_x  = (const float*)d_in[1];
  const float* cand_y  = (const float*)d_in[2];
  // d_in[3] = context_size (device scalar, value is always CTX=96)
  const float* lin_W   = (const float*)d_in[4];
  const float* lin_b   = (const float*)d_in[5];
  const float* e0_W1   = (const float*)d_in[6];
  const float* e0_b1   = (const float*)d_in[7];
  const float* e0_W2   = (const float*)d_in[8];
  const float* e0_b2   = (const float*)d_in[9];
  const float* e1_g    = (const float*)d_in[10];
  const float* e1_b    = (const float*)d_in[11];
  const float* e1_W1   = (const float*)d_in[12];
  const float* e1_b1   = (const float*)d_in[13];
  const float* e1_W2   = (const float*)d_in[14];
  const float* e1_b2   = (const float*)d_in[15];
  const float* mix_g   = (const float*)d_in[16];
  const float* mix_b   = (const float*)d_in[17];
  const float* K_W     = (const float*)d_in[18];
  const float* K_b     = (const float*)d_in[19];
  const float* T_W1    = (const float*)d_in[20];
  const float* T_b1    = (const float*)d_in[21];
  const float* T_W2    = (const float*)d_in[22];
  const float* lab_w   = (const float*)d_in[23];
  const float* lab_b   = (const float*)d_in[24];
  const float* p0_g    = (const float*)d_in[25];
  const float* p0_b    = (const float*)d_in[26];
  const float* p0_W1   = (const float*)d_in[27];
  const float* p0_b1   = (const float*)d_in[28];
  const float* p0_W2   = (const float*)d_in[29];
  const float* p0_b2   = (const float*)d_in[30];
  const float* head_g  = (const float*)d_in[31];
  const float* head_b  = (const float*)d_in[32];
  const float* head_W  = (const float*)d_in[33];
  const float* head_bias = (const float*)d_in[34];
  float* out = (float*)d_out;

  const int N = in_sizes[1] / D_IN;
  const int B = in_sizes[0] / D_IN;
  const int Npad = ((N + SC_BJ - 1) / SC_BJ) * SC_BJ;

  char* p = (char*)d_ws;
  auto take = [&](size_t bytes) {
    char* q = p;
    p += (bytes + 255) & ~(size_t)255;
    return q;
  };
  float*  ck      = (float*)take((size_t)N * D_MAIN * sizeof(float));
  float*  cknorm  = (float*)take((size_t)N * sizeof(float));
  float*  xh      = (float*)take((size_t)B * D_MAIN * sizeof(float));
  float*  xk      = (float*)take((size_t)B * D_MAIN * sizeof(float));
  __half* S       = (__half*)take((size_t)B * Npad * sizeof(__half));
  int*    ctxidx  = (int*)take((size_t)B * CTX * sizeof(int));
  (void)ws_size; (void)n_in; (void)out_size;

  const int encC = (N + ENC_ROWS - 1) / ENC_ROWS;
  encode_kernel<<<encC, 256, 0, stream>>>(
      cand_x, N, lin_W, lin_b, e0_W1, e0_b1, e0_W2, e0_b2,
      e1_g, e1_b, e1_W1, e1_b1, e1_W2, e1_b2,
      mix_g, mix_b, K_W, K_b, ck, cknorm, nullptr);

  const int encB = (B + ENC_ROWS - 1) / ENC_ROWS;
  encode_kernel<<<encB, 256, 0, stream>>>(
      x_num, B, lin_W, lin_b, e0_W1, e0_b1, e0_W2, e0_b2,
      e1_g, e1_b, e1_W1, e1_b1, e1_W2, e1_b2,
      mix_g, mix_b, K_W, K_b, xk, nullptr, xh);

  dim3 sg(Npad / SC_BJ, (B + SC_BR - 1) / SC_BR);
  score_kernel<<<sg, 256, 0, stream>>>(xk, ck, cknorm, N, Npad, B, S);

  topk_kernel<<<B, 256, 0, stream>>>(S, N, Npad, ctxidx);

  finalize_kernel<<<B, 256, 0, stream>>>(
      xh, xk, ck, cand_y, ctxidx,
      T_W1, T_b1, T_W2, lab_w, lab_b,
      p0_g, p0_b, p0_W1, p0_b1, p0_W2, p0_b2,
      head_g, head_b, head_W, head_bias, out);
}

// Round 2
// 1124.417 us; speedup vs baseline: 1.5222x; 1.5222x over previous
//
#include <hip/hip_runtime.h>
#include <hip/hip_fp16.h>
#include <float.h>
#include <math.h>

#define D_IN 32
#define D_MAIN 128
#define D_BLOCK 256
#define CTX 96
#define LN_EPS 1e-5f

typedef short bf16x8 __attribute__((ext_vector_type(8)));
typedef float f32x4 __attribute__((ext_vector_type(4)));
typedef unsigned short ushort4v __attribute__((ext_vector_type(4)));

__device__ __forceinline__ unsigned short f2bf(float x) {
  union { float f; unsigned u; } v; v.f = x;
  const unsigned r = (v.u + 0x7FFFu + ((v.u >> 16) & 1u)) >> 16;
  return (unsigned short)r;
}

// ---------------------------------------------------------------------------
// Pack a K x N fp32 weight matrix into MFMA B-fragment order (bf16):
// frag f = j*(K/32)+s ; lane l holds B[k=32s+(l>>4)*8+jj][n=16j+(l&15)], jj=0..7
// ---------------------------------------------------------------------------
__global__ __launch_bounds__(256) void pack_w_kernel(
    const float* __restrict__ W, int K, int N, unsigned short* __restrict__ out)
{
  const int tid = blockIdx.x * 256 + threadIdx.x;
  const int ks = K / 32;
  const int total = (N / 16) * ks * 64;
  if (tid >= total) return;
  const int l = tid & 63, f = tid >> 6;
  const int s = f % ks, j = f / ks;
  const int kb = s * 32 + (l >> 4) * 8;
  const int n = j * 16 + (l & 15);
  unsigned short v[8];
#pragma unroll
  for (int jj = 0; jj < 8; ++jj) v[jj] = f2bf(W[(size_t)(kb + jj) * N + n]);
  ushort4v* o = (ushort4v*)(out + (size_t)tid * 8);
  ushort4v u0 = {v[0], v[1], v[2], v[3]};
  ushort4v u1 = {v[4], v[5], v[6], v[7]};
  o[0] = u0; o[1] = u1;
}

// ---------------------------------------------------------------------------
// MFMA encoder. Block = 128 rows, 4 waves (mw = row-half, nw = col-half).
// h resides in C-layout registers; A operands staged bf16 in LDS.
// ---------------------------------------------------------------------------
#define LDA 136   // A-region stride (shorts); 272 B row stride, 16B aligned
#define LDU 72    // relu-chunk stride (shorts)

struct EncShared {
  unsigned short As[128 * LDA];
  unsigned short Us[128 * LDU];
  float lsum[2][128];
  float lssq[2][128];
  float smu[128];
  float srs[128];
};

__device__ __forceinline__ void enc_block(
    f32x4 (&h)[4][4], EncShared& sh,
    const unsigned short* __restrict__ W1_pk, const float* __restrict__ b1,
    const unsigned short* __restrict__ W2_pk, const float* __restrict__ b2,
    int mrow, int nw, int c, int q, int lane)
{
  // As holds the block's A input (h or LN(h)) bf16 [128][LDA]
#pragma unroll 1
  for (int ch = 0; ch < 4; ++ch) {
    // phase A: relu chunk, output cols [ch*64, ch*64+64)
    f32x4 u[4][2];
#pragma unroll
    for (int mi = 0; mi < 4; ++mi)
#pragma unroll
      for (int ntl = 0; ntl < 2; ++ntl) { f32x4 z = {0.f,0.f,0.f,0.f}; u[mi][ntl] = z; }
#pragma unroll 1
    for (int s = 0; s < 4; ++s) {
      bf16x8 a[4];
#pragma unroll
      for (int mi = 0; mi < 4; ++mi)
        a[mi] = *(const bf16x8*)&sh.As[(mrow + mi*16 + c) * LDA + s*32 + q*8];
#pragma unroll
      for (int ntl = 0; ntl < 2; ++ntl) {
        const int j = ch*4 + nw*2 + ntl;
        const bf16x8 b = *(const bf16x8*)&W1_pk[((size_t)(j*4 + s) * 64 + lane) * 8];
#pragma unroll
        for (int mi = 0; mi < 4; ++mi)
          u[mi][ntl] = __builtin_amdgcn_mfma_f32_16x16x32_bf16(a[mi], b, u[mi][ntl], 0, 0, 0);
      }
    }
#pragma unroll
    for (int ntl = 0; ntl < 2; ++ntl) {
      const int colg = ch*64 + nw*32 + ntl*16 + c;
      const float bb = b1[colg];
      const int coll = nw*32 + ntl*16 + c;
#pragma unroll
      for (int mi = 0; mi < 4; ++mi)
#pragma unroll
        for (int r = 0; r < 4; ++r)
          sh.Us[(mrow + mi*16 + q*4 + r) * LDU + coll] = f2bf(fmaxf(u[mi][ntl][r] + bb, 0.f));
    }
    __syncthreads();
    // phase B: h += Us @ W2[k-chunk ch]
#pragma unroll 1
    for (int s2 = 0; s2 < 2; ++s2) {
      bf16x8 a2[4];
#pragma unroll
      for (int mi = 0; mi < 4; ++mi)
        a2[mi] = *(const bf16x8*)&sh.Us[(mrow + mi*16 + c) * LDU + s2*32 + q*8];
#pragma unroll
      for (int nt = 0; nt < 4; ++nt) {
        const int j2 = nw*4 + nt;
        const bf16x8 b = *(const bf16x8*)&W2_pk[((size_t)(j2*8 + ch*2 + s2) * 64 + lane) * 8];
#pragma unroll
        for (int mi = 0; mi < 4; ++mi)
          h[mi][nt] = __builtin_amdgcn_mfma_f32_16x16x32_bf16(a2[mi], b, h[mi][nt], 0, 0, 0);
      }
    }
    __syncthreads();
  }
#pragma unroll
  for (int nt = 0; nt < 4; ++nt) {
    const float bb = b2[nw*64 + nt*16 + c];
#pragma unroll
    for (int mi = 0; mi < 4; ++mi) {
      h[mi][nt][0] += bb; h[mi][nt][1] += bb; h[mi][nt][2] += bb; h[mi][nt][3] += bb;
    }
  }
}

// LN over register-resident h; writes LN'd h (bf16) into As.
__device__ __forceinline__ void enc_ln_regs(
    f32x4 (&h)[4][4], EncShared& sh,
    const float* __restrict__ g, const float* __restrict__ bv,
    int mrow, int nw, int c, int q, int t)
{
  float ps[4][4], pss[4][4];
#pragma unroll
  for (int mi = 0; mi < 4; ++mi)
#pragma unroll
    for (int r = 0; r < 4; ++r) {
      float s = 0.f, ss = 0.f;
#pragma unroll
      for (int nt = 0; nt < 4; ++nt) { const float v = h[mi][nt][r]; s += v; ss += v * v; }
      ps[mi][r] = s; pss[mi][r] = ss;
    }
#pragma unroll
  for (int off = 1; off < 16; off <<= 1) {
#pragma unroll
    for (int mi = 0; mi < 4; ++mi)
#pragma unroll
      for (int r = 0; r < 4; ++r) {
        ps[mi][r] += __shfl_xor(ps[mi][r], off, 64);
        pss[mi][r] += __shfl_xor(pss[mi][r], off, 64);
      }
  }
#pragma unroll
  for (int r = 0; r < 4; ++r) {
    if (c == r) {
#pragma unroll
      for (int mi = 0; mi < 4; ++mi) {
        const int row = mrow + mi*16 + q*4 + r;
        sh.lsum[nw][row] = ps[mi][r];
        sh.lssq[nw][row] = pss[mi][r];
      }
    }
  }
  __syncthreads();
  if (t < 128) {
    const float s = sh.lsum[0][t] + sh.lsum[1][t];
    const float ss = sh.lssq[0][t] + sh.lssq[1][t];
    const float mu = s * (1.f / 128.f);
    const float var = ss * (1.f / 128.f) - mu * mu;
    sh.smu[t] = mu;
    sh.srs[t] = rsqrtf(var + LN_EPS);
  }
  __syncthreads();
#pragma unroll
  for (int nt = 0; nt < 4; ++nt) {
    const int col = nw*64 + nt*16 + c;
    const float gg = g[col], bb = bv[col];
#pragma unroll
    for (int mi = 0; mi < 4; ++mi)
#pragma unroll
      for (int r = 0; r < 4; ++r) {
        const int row = mrow + mi*16 + q*4 + r;
        sh.As[row * LDA + col] = f2bf((h[mi][nt][r] - sh.smu[row]) * sh.srs[row] * gg + bb);
      }
  }
  __syncthreads();
}

__global__ __launch_bounds__(256, 2) void encode_mfma(
    const float* __restrict__ xin, int nrows,
    const unsigned short* __restrict__ linW_pk, const float* __restrict__ lin_b,
    const unsigned short* __restrict__ e0W1_pk, const float* __restrict__ e0_b1,
    const unsigned short* __restrict__ e0W2_pk, const float* __restrict__ e0_b2,
    const float* __restrict__ e1_g, const float* __restrict__ e1_b,
    const unsigned short* __restrict__ e1W1_pk, const float* __restrict__ e1_b1,
    const unsigned short* __restrict__ e1W2_pk, const float* __restrict__ e1_b2,
    const float* __restrict__ mix_g, const float* __restrict__ mix_b,
    const unsigned short* __restrict__ KW_pk, const float* __restrict__ K_b,
    float* __restrict__ k_out, float* __restrict__ knorm_out,
    float* __restrict__ h_out)
{
  __shared__ EncShared sh;
  const int t = threadIdx.x, lane = t & 63, w = t >> 6;
  const int mw = w & 1, nw = w >> 1;
  const int c = lane & 15, q = lane >> 4;
  const int mrow = mw * 64;
  const int row0 = blockIdx.x * 128;

  // stage x -> As bf16 (stride LDA, cols 0..31)
  for (int i = t; i < 128 * 8; i += 256) {
    const int r = i >> 3, c4 = (i & 7) * 4;
    const int gr = row0 + r;
    float4 v = make_float4(0.f, 0.f, 0.f, 0.f);
    if (gr < nrows) v = *(const float4*)&xin[(size_t)gr * D_IN + c4];
    ushort4v u = {f2bf(v.x), f2bf(v.y), f2bf(v.z), f2bf(v.w)};
    *(ushort4v*)&sh.As[r * LDA + c4] = u;
  }
  __syncthreads();

  f32x4 h[4][4];
  // input linear: K=32 (1 k-step), N=128
  {
    bf16x8 a[4];
#pragma unroll
    for (int mi = 0; mi < 4; ++mi)
      a[mi] = *(const bf16x8*)&sh.As[(mrow + mi*16 + c) * LDA + q*8];
#pragma unroll
    for (int nt = 0; nt < 4; ++nt) {
      const int j = nw*4 + nt;
      const bf16x8 b = *(const bf16x8*)&linW_pk[((size_t)j * 64 + lane) * 8];
      const float bb = lin_b[j*16 + c];
#pragma unroll
      for (int mi = 0; mi < 4; ++mi) {
        f32x4 z = {0.f, 0.f, 0.f, 0.f};
        z = __builtin_amdgcn_mfma_f32_16x16x32_bf16(a[mi], b, z, 0, 0, 0);
        z[0] += bb; z[1] += bb; z[2] += bb; z[3] += bb;
        h[mi][nt] = z;
      }
    }
  }
  __syncthreads();   // all waves done reading x region
  // write h (identity A for e0) -> As
#pragma unroll
  for (int nt = 0; nt < 4; ++nt)
#pragma unroll
    for (int mi = 0; mi < 4; ++mi)
#pragma unroll
      for (int r = 0; r < 4; ++r)
        sh.As[(mrow + mi*16 + q*4 + r) * LDA + nw*64 + nt*16 + c] = f2bf(h[mi][nt][r]);
  __syncthreads();

  enc_block(h, sh, e0W1_pk, e0_b1, e0W2_pk, e0_b2, mrow, nw, c, q, lane);
  enc_ln_regs(h, sh, e1_g, e1_b, mrow, nw, c, q, t);
  enc_block(h, sh, e1W1_pk, e1_b1, e1W2_pk, e1_b2, mrow, nw, c, q, lane);
  enc_ln_regs(h, sh, mix_g, mix_b, mrow, nw, c, q, t);

  // K projection: N=128, K=128
  f32x4 kk[4][4];
#pragma unroll
  for (int mi = 0; mi < 4; ++mi)
#pragma unroll
    for (int nt = 0; nt < 4; ++nt) { f32x4 z = {0.f,0.f,0.f,0.f}; kk[mi][nt] = z; }
#pragma unroll 1
  for (int s = 0; s < 4; ++s) {
    bf16x8 a[4];
#pragma unroll
    for (int mi = 0; mi < 4; ++mi)
      a[mi] = *(const bf16x8*)&sh.As[(mrow + mi*16 + c) * LDA + s*32 + q*8];
#pragma unroll
    for (int nt = 0; nt < 4; ++nt) {
      const int j = nw*4 + nt;
      const bf16x8 b = *(const bf16x8*)&KW_pk[((size_t)(j*4 + s) * 64 + lane) * 8];
#pragma unroll
      for (int mi = 0; mi < 4; ++mi)
        kk[mi][nt] = __builtin_amdgcn_mfma_f32_16x16x32_bf16(a[mi], b, kk[mi][nt], 0, 0, 0);
    }
  }
#pragma unroll
  for (int nt = 0; nt < 4; ++nt) {
    const int col = nw*64 + nt*16 + c;
    const float bb = K_b[col];
#pragma unroll
    for (int mi = 0; mi < 4; ++mi)
#pragma unroll
      for (int r = 0; r < 4; ++r) {
        kk[mi][nt][r] += bb;
        const int gr = row0 + mrow + mi*16 + q*4 + r;
        if (gr < nrows) k_out[(size_t)gr * D_MAIN + col] = kk[mi][nt][r];
      }
  }
  if (h_out) {
#pragma unroll
    for (int nt = 0; nt < 4; ++nt) {
      const int col = nw*64 + nt*16 + c;
#pragma unroll
      for (int mi = 0; mi < 4; ++mi)
#pragma unroll
        for (int r = 0; r < 4; ++r) {
          const int gr = row0 + mrow + mi*16 + q*4 + r;
          if (gr < nrows) h_out[(size_t)gr * D_MAIN + col] = h[mi][nt][r];
        }
    }
  }
  if (knorm_out) {
    float pss[4][4];
#pragma unroll
    for (int mi = 0; mi < 4; ++mi)
#pragma unroll
      for (int r = 0; r < 4; ++r) {
        float ss = 0.f;
#pragma unroll
        for (int nt = 0; nt < 4; ++nt) { const float v = kk[mi][nt][r]; ss += v * v; }
        pss[mi][r] = ss;
      }
#pragma unroll
    for (int off = 1; off < 16; off <<= 1)
#pragma unroll
      for (int mi = 0; mi < 4; ++mi)
#pragma unroll
        for (int r = 0; r < 4; ++r)
          pss[mi][r] += __shfl_xor(pss[mi][r], off, 64);
#pragma unroll
    for (int r = 0; r < 4; ++r) {
      if (c == r) {
#pragma unroll
        for (int mi = 0; mi < 4; ++mi)
          sh.lssq[nw][mrow + mi*16 + q*4 + r] = pss[mi][r];
      }
    }
    __syncthreads();
    if (t < 128) {
      const int gr = row0 + t;
      if (gr < nrows) knorm_out[gr] = sh.lssq[0][t] + sh.lssq[1][t];
    }
  }
}

// ---------------------------------------------------------------------------
// Score: S[b][j] = 2*dot(xk[b], ck[j]) - ||ck[j]||^2, fp16. MFMA bf16.
// Block = 64 query rows x 256 candidates (wave = 64x64).
// ---------------------------------------------------------------------------
__global__ __launch_bounds__(256) void score_mfma(
    const float* __restrict__ xk, const float* __restrict__ ck,
    const float* __restrict__ cknorm, int N, int Npad,
    __half* __restrict__ S)
{
  __shared__ unsigned short Ks[64 * 136];
  const int t = threadIdx.x, lane = t & 63, w = t >> 6;
  const int c = lane & 15, q = lane >> 4;
  const int b0 = blockIdx.y * 64;
  const int n0 = blockIdx.x * 256 + w * 64;

  for (int i = t; i < 64 * 32; i += 256) {
    const int r = i >> 5, c4 = (i & 31) * 4;
    const float4 v = *(const float4*)&xk[(size_t)(b0 + r) * D_MAIN + c4];
    ushort4v u = {f2bf(v.x), f2bf(v.y), f2bf(v.z), f2bf(v.w)};
    *(ushort4v*)&Ks[r * 136 + c4] = u;
  }
  __syncthreads();

  f32x4 acc[4][4];
#pragma unroll
  for (int mi = 0; mi < 4; ++mi)
#pragma unroll
    for (int nt = 0; nt < 4; ++nt) { f32x4 z = {0.f,0.f,0.f,0.f}; acc[mi][nt] = z; }

#pragma unroll 1
  for (int s = 0; s < 4; ++s) {
    bf16x8 a[4];
#pragma unroll
    for (int mi = 0; mi < 4; ++mi)
      a[mi] = *(const bf16x8*)&Ks[(mi*16 + c) * 136 + s*32 + q*8];
#pragma unroll
    for (int nt = 0; nt < 4; ++nt) {
      const size_t n = (size_t)(n0 + nt*16 + c);
      const float4 v0 = *(const float4*)&ck[n * D_MAIN + s*32 + q*8];
      const float4 v1 = *(const float4*)&ck[n * D_MAIN + s*32 + q*8 + 4];
      bf16x8 b;
      b[0] = (short)f2bf(v0.x); b[1] = (short)f2bf(v0.y);
      b[2] = (short)f2bf(v0.z); b[3] = (short)f2bf(v0.w);
      b[4] = (short)f2bf(v1.x); b[5] = (short)f2bf(v1.y);
      b[6] = (short)f2bf(v1.z); b[7] = (short)f2bf(v1.w);
#pragma unroll
      for (int mi = 0; mi < 4; ++mi)
        acc[mi][nt] = __builtin_amdgcn_mfma_f32_16x16x32_bf16(a[mi], b, acc[mi][nt], 0, 0, 0);
    }
  }
#pragma unroll
  for (int nt = 0; nt < 4; ++nt) {
    const int col = n0 + nt*16 + c;
    if (col < N) {
      const float cn = cknorm[col];
#pragma unroll
      for (int mi = 0; mi < 4; ++mi)
#pragma unroll
        for (int r = 0; r < 4; ++r) {
          const int row = b0 + mi*16 + q*4 + r;
          S[(size_t)row * Npad + col] = __float2half(2.f * acc[mi][nt][r] - cn);
        }
    }
  }
}

// ---------------------------------------------------------------------------
// Top-K per row: 2-level histogram threshold -> collect -> bitonic sort.
// ---------------------------------------------------------------------------
#define TK_BINS 1024
#define TK_CAP 2048

__global__ __launch_bounds__(256) void topk_kernel(
    const __half* __restrict__ S, int N, int Npad, int* __restrict__ idx_out)
{
  __shared__ int hist[TK_BINS];
  __shared__ float sbuf[TK_CAP];
  __shared__ int ibuf[TK_CAP];
  __shared__ float red[256];
  __shared__ float s_mn, s_inv1, s_lo1, s_inv2;
  __shared__ int s_B1, s_B2, s_cab, s_count;
  const int t = threadIdx.x;
  const int b = blockIdx.x;
  const __half* row = S + (size_t)b * Npad;

  float mn = FLT_MAX, mx = -FLT_MAX;
  for (int j = t; j < N; j += 256) {
    const float v = __half2float(row[j]);
    mn = fminf(mn, v);
    mx = fmaxf(mx, v);
  }
  red[t] = mx;
  __syncthreads();
  for (int o = 128; o > 0; o >>= 1) {
    if (t < o) red[t] = fmaxf(red[t], red[t + o]);
    __syncthreads();
  }
  const float gmx = red[0];
  __syncthreads();
  red[t] = mn;
  __syncthreads();
  for (int o = 128; o > 0; o >>= 1) {
    if (t < o) red[t] = fminf(red[t], red[t + o]);
    __syncthreads();
  }
  if (t == 0) {
    s_mn = red[0];
    const float range = fmaxf(gmx - red[0], 1e-20f);
    s_inv1 = (float)TK_BINS / range;
  }
  __syncthreads();
  const float bmn = s_mn, inv1 = s_inv1;

  for (int i = t; i < TK_BINS; i += 256) hist[i] = 0;
  __syncthreads();
  for (int j = t; j < N; j += 256) {
    const float v = __half2float(row[j]);
    int bin = (int)((v - bmn) * inv1);
    bin = min(max(bin, 0), TK_BINS - 1);
    atomicAdd(&hist[bin], 1);
  }
  __syncthreads();
  if (t == 0) {
    int cc = 0, B1 = 0;
    for (int qq = TK_BINS - 1; qq >= 0; --qq) {
      cc += hist[qq];
      if (cc >= CTX) { B1 = qq; break; }
    }
    s_B1 = B1;
    s_cab = cc - hist[B1];
    s_lo1 = bmn + (float)B1 / inv1;
    s_inv2 = inv1 * (float)TK_BINS;
  }
  __syncthreads();
  const int B1 = s_B1;
  const float lo1 = s_lo1, inv2 = s_inv2;

  for (int i = t; i < TK_BINS; i += 256) hist[i] = 0;
  __syncthreads();
  for (int j = t; j < N; j += 256) {
    const float v = __half2float(row[j]);
    int bin = (int)((v - bmn) * inv1);
    bin = min(max(bin, 0), TK_BINS - 1);
    if (bin == B1) {
      int b2 = (int)((v - lo1) * inv2);
      b2 = min(max(b2, 0), TK_BINS - 1);
      atomicAdd(&hist[b2], 1);
    }
  }
  __syncthreads();
  if (t == 0) {
    int cc = s_cab, B2 = 0;
    for (int qq = TK_BINS - 1; qq >= 0; --qq) {
      cc += hist[qq];
      if (cc >= CTX) { B2 = qq; break; }
    }
    s_B2 = B2;
    s_count = 0;
  }
  __syncthreads();
  const int B2 = s_B2;

  for (int j = t; j < N; j += 256) {
    const float v = __half2float(row[j]);
    int bin = (int)((v - bmn) * inv1);
    bin = min(max(bin, 0), TK_BINS - 1);
    bool take = (bin > B1);
    if (bin == B1) {
      int b2 = (int)((v - lo1) * inv2);
      b2 = min(max(b2, 0), TK_BINS - 1);
      take = (b2 >= B2);
    }
    if (take) {
      const int pos = atomicAdd(&s_count, 1);
      if (pos < TK_CAP) { sbuf[pos] = v; ibuf[pos] = j; }
    }
  }
  __syncthreads();
  const int m = min(s_count, TK_CAP);
  for (int i = t; i < TK_CAP; i += 256) {
    if (i >= m) { sbuf[i] = -FLT_MAX; ibuf[i] = 0x7FFFFFFF; }
  }
  __syncthreads();
  for (int k = 2; k <= TK_CAP; k <<= 1) {
    for (int stride = k >> 1; stride > 0; stride >>= 1) {
      for (int i = t; i < TK_CAP; i += 256) {
        const int ixj = i ^ stride;
        if (ixj > i) {
          const float sa = sbuf[i], sb = sbuf[ixj];
          const int ia = ibuf[i], ib = ibuf[ixj];
          const bool before = (sa > sb) || (sa == sb && ia < ib);
          const bool want = ((i & k) == 0);
          if (before != want) {
            sbuf[i] = sb; sbuf[ixj] = sa;
            ibuf[i] = ib; ibuf[ixj] = ia;
          }
        }
      }
      __syncthreads();
    }
  }
  if (t < CTX) idx_out[b * CTX + t] = ibuf[t];
}

// ---------------------------------------------------------------------------
// Finalize: exact sims + softmax, T-module (4 neighbors/pass), label encoder,
// predictor block, head. One block per query row.
// ---------------------------------------------------------------------------
__global__ __launch_bounds__(256) void finalize_kernel(
    const float* __restrict__ xh, const float* __restrict__ xk,
    const float* __restrict__ ck, const float* __restrict__ cand_y,
    const int* __restrict__ ctx_idx,
    const float* __restrict__ T_W1, const float* __restrict__ T_b1,
    const float* __restrict__ T_W2,
    const float* __restrict__ lab_w, const float* __restrict__ lab_b,
    const float* __restrict__ p0_g, const float* __restrict__ p0_b,
    const float* __restrict__ p0_W1, const float* __restrict__ p0_b1,
    const float* __restrict__ p0_W2, const float* __restrict__ p0_b2,
    const float* __restrict__ head_g, const float* __restrict__ head_b,
    const float* __restrict__ head_W, const float* __restrict__ head_bias,
    float* __restrict__ out)
{
  const int CKP = D_MAIN + 1;
  __shared__ float ckc[CTX * (D_MAIN + 1)];
  __shared__ float kb[D_MAIN], xr[D_MAIN], accv[D_MAIN];
  __shared__ float diffs[4][D_MAIN];
  __shared__ float ubuf[4][D_BLOCK];
  __shared__ float vbuf[4][D_BLOCK];
  __shared__ float probs[CTX], ys[CTX];
  __shared__ int idxs[CTX];
  __shared__ float s_scalar[4];
  const int t = threadIdx.x;
  const int b = blockIdx.x;

  if (t < CTX) {
    const int j = ctx_idx[b * CTX + t];
    idxs[t] = j;
    ys[t] = cand_y[j];
  }
  if (t < D_MAIN) {
    kb[t] = xk[(size_t)b * D_MAIN + t];
    xr[t] = xh[(size_t)b * D_MAIN + t];
    accv[t] = 0.f;
  }
  __syncthreads();
  for (int i = t; i < CTX * D_MAIN; i += 256) {
    const int r = i >> 7, c = i & 127;
    ckc[r * CKP + c] = ck[(size_t)idxs[r] * D_MAIN + c];
  }
  __syncthreads();
  if (t < CTX) {
    float s = 0.f;
    for (int c = 0; c < D_MAIN; ++c) {
      const float d = kb[c] - ckc[t * CKP + c];
      s += d * d;
    }
    probs[t] = -s;
  }
  __syncthreads();
  if (t == 0) {
    float mval = -FLT_MAX;
    for (int i = 0; i < CTX; ++i) mval = fmaxf(mval, probs[i]);
    float sum = 0.f;
    for (int i = 0; i < CTX; ++i) {
      const float e = expf(probs[i] - mval);
      probs[i] = e;
      sum += e;
    }
    const float inv = 1.f / sum;
    float sy = 0.f;
    for (int i = 0; i < CTX; ++i) {
      probs[i] *= inv;
      sy += probs[i] * ys[i];
    }
    s_scalar[0] = sy;
  }
  __syncthreads();

  for (int jb = 0; jb < CTX; jb += 4) {
    for (int i = t; i < 4 * D_MAIN; i += 256) {
      const int jj = i >> 7, c = i & 127;
      diffs[jj][c] = kb[c] - ckc[(jb + jj) * CKP + c];
    }
    __syncthreads();
    {
      float u[4] = {0.f, 0.f, 0.f, 0.f};
      for (int c = 0; c < D_MAIN; c += 4) {
        const float w0 = T_W1[(c + 0) * D_BLOCK + t];
        const float w1 = T_W1[(c + 1) * D_BLOCK + t];
        const float w2 = T_W1[(c + 2) * D_BLOCK + t];
        const float w3 = T_W1[(c + 3) * D_BLOCK + t];
#pragma unroll
        for (int jj = 0; jj < 4; ++jj) {
          const float4 d4 = *(const float4*)&diffs[jj][c];
          u[jj] += d4.x * w0 + d4.y * w1 + d4.z * w2 + d4.w * w3;
        }
      }
      const float bb = T_b1[t];
#pragma unroll
      for (int jj = 0; jj < 4; ++jj) ubuf[jj][t] = fmaxf(u[jj] + bb, 0.f);
    }
    __syncthreads();
    {
      const int c = t & 127;
      const int d0 = (t >> 7) * 128;
      float v[4] = {0.f, 0.f, 0.f, 0.f};
      for (int d = d0; d < d0 + 128; d += 4) {
        const float w0 = T_W2[(d + 0) * D_MAIN + c];
        const float w1 = T_W2[(d + 1) * D_MAIN + c];
        const float w2 = T_W2[(d + 2) * D_MAIN + c];
        const float w3 = T_W2[(d + 3) * D_MAIN + c];
#pragma unroll
        for (int jj = 0; jj < 4; ++jj) {
          const float4 u4 = *(const float4*)&ubuf[jj][d];
          v[jj] += u4.x * w0 + u4.y * w1 + u4.z * w2 + u4.w * w3;
        }
      }
#pragma unroll
      for (int jj = 0; jj < 4; ++jj) vbuf[jj][t] = v[jj];
    }
    __syncthreads();
    if (t < D_MAIN) {
      float a = accv[t];
#pragma unroll
      for (int jj = 0; jj < 4; ++jj)
        a += probs[jb + jj] * (vbuf[jj][t] + vbuf[jj][t + 128]);
      accv[t] = a;
    }
    __syncthreads();
  }
  if (t < D_MAIN)
    xr[t] = xr[t] + accv[t] + s_scalar[0] * lab_w[t] + lab_b[t];
  __syncthreads();
  if (t == 0) {
    float s = 0.f, ss = 0.f;
    for (int c = 0; c < D_MAIN; ++c) { const float v = xr[c]; s += v; ss += v * v; }
    const float mu = s / D_MAIN;
    s_scalar[1] = mu;
    s_scalar[2] = rsqrtf(ss / D_MAIN - mu * mu + LN_EPS);
  }
  __syncthreads();
  if (t < D_MAIN)
    diffs[0][t] = (xr[t] - s_scalar[1]) * s_scalar[2] * p0_g[t] + p0_b[t];
  __syncthreads();
  {
    float u = 0.f;
    for (int c = 0; c < D_MAIN; c += 4) {
      const float w0 = p0_W1[(c + 0) * D_BLOCK + t];
      const float w1 = p0_W1[(c + 1) * D_BLOCK + t];
      const float w2 = p0_W1[(c + 2) * D_BLOCK + t];
      const float w3 = p0_W1[(c + 3) * D_BLOCK + t];
      const float4 d4 = *(const float4*)&diffs[0][c];
      u += d4.x * w0 + d4.y * w1 + d4.z * w2 + d4.w * w3;
    }
    ubuf[0][t] = fmaxf(u + p0_b1[t], 0.f);
  }
  __syncthreads();
  {
    const int c = t & 127;
    const int d0 = (t >> 7) * 128;
    float v = 0.f;
    for (int d = d0; d < d0 + 128; d += 4) {
      const float w0 = p0_W2[(d + 0) * D_MAIN + c];
      const float w1 = p0_W2[(d + 1) * D_MAIN + c];
      const float w2 = p0_W2[(d + 2) * D_MAIN + c];
      const float w3 = p0_W2[(d + 3) * D_MAIN + c];
      const float4 u4 = *(const float4*)&ubuf[0][d];
      v += u4.x * w0 + u4.y * w1 + u4.z * w2 + u4.w * w3;
    }
    vbuf[0][t] = v;
  }
  __syncthreads();
  if (t < D_MAIN) xr[t] += vbuf[0][t] + vbuf[0][t + 128] + p0_b2[t];
  __syncthreads();
  if (t == 0) {
    float s = 0.f, ss = 0.f;
    for (int c = 0; c < D_MAIN; ++c) { const float v = xr[c]; s += v; ss += v * v; }
    const float mu = s / D_MAIN;
    s_scalar[1] = mu;
    s_scalar[2] = rsqrtf(ss / D_MAIN - mu * mu + LN_EPS);
  }
  __syncthreads();
  if (t < D_MAIN) {
    float hv = (xr[t] - s_scalar[1]) * s_scalar[2] * head_g[t] + head_b[t];
    hv = fmaxf(hv, 0.f);
    diffs[0][t] = hv * head_W[t];
  }
  __syncthreads();
  if (t == 0) {
    float s = 0.f;
    for (int c = 0; c < D_MAIN; ++c) s += diffs[0][c];
    out[b] = s + head_bias[0];
  }
}

// ---------------------------------------------------------------------------
extern "C" void kernel_launch(void* const* d_in, const int* in_sizes, int n_in,
                              void* d_out, int out_size, void* d_ws, size_t ws_size,
                              hipStream_t stream)
{
  const float* x_num   = (const float*)d_in[0];
  const float* cand_x  = (const float*)d_in[1];
  const float* cand_y  = (const float*)d_in[2];
  const float* lin_W   = (const float*)d_in[4];
  const float* lin_b   = (const float*)d_in[5];
  const float* e0_W1   = (const float*)d_in[6];
  const float* e0_b1   = (const float*)d_in[7];
  const float* e0_W2   = (const float*)d_in[8];
  const float* e0_b2   = (const float*)d_in[9];
  const float* e1_g    = (const float*)d_in[10];
  const float* e1_b    = (const float*)d_in[11];
  const float* e1_W1   = (const float*)d_in[12];
  const float* e1_b1   = (const float*)d_in[13];
  const float* e1_W2   = (const float*)d_in[14];
  const float* e1_b2   = (const float*)d_in[15];
  const float* mix_g   = (const float*)d_in[16];
  const float* mix_b   = (const float*)d_in[17];
  const float* K_W     = (const float*)d_in[18];
  const float* K_b     = (const float*)d_in[19];
  const float* T_W1    = (const float*)d_in[20];
  const float* T_b1    = (const float*)d_in[21];
  const float* T_W2    = (const float*)d_in[22];
  const float* lab_w   = (const float*)d_in[23];
  const float* lab_b   = (const float*)d_in[24];
  const float* p0_g    = (const float*)d_in[25];
  const float* p0_b    = (const float*)d_in[26];
  const float* p0_W1   = (const float*)d_in[27];
  const float* p0_b1   = (const float*)d_in[28];
  const float* p0_W2   = (const float*)d_in[29];
  const float* p0_b2   = (const float*)d_in[30];
  const float* head_g  = (const float*)d_in[31];
  const float* head_b  = (const float*)d_in[32];
  const float* head_W  = (const float*)d_in[33];
  const float* head_bias = (const float*)d_in[34];
  float* out = (float*)d_out;

  const int N = in_sizes[1] / D_IN;
  const int B = in_sizes[0] / D_IN;
  const int Npad = ((N + 255) / 256) * 256;

  char* p = (char*)d_ws;
  auto take = [&](size_t bytes) {
    char* q = p;
    p += (bytes + 255) & ~(size_t)255;
    return q;
  };
  unsigned short* pk_lin  = (unsigned short*)take(32  * 128 * 2);
  unsigned short* pk_e0w1 = (unsigned short*)take(128 * 256 * 2);
  unsigned short* pk_e0w2 = (unsigned short*)take(256 * 128 * 2);
  unsigned short* pk_e1w1 = (unsigned short*)take(128 * 256 * 2);
  unsigned short* pk_e1w2 = (unsigned short*)take(256 * 128 * 2);
  unsigned short* pk_kw   = (unsigned short*)take(128 * 128 * 2);
  float*  ck      = (float*)take((size_t)Npad * D_MAIN * sizeof(float));
  float*  cknorm  = (float*)take((size_t)N * sizeof(float));
  float*  xh      = (float*)take((size_t)B * D_MAIN * sizeof(float));
  float*  xk      = (float*)take((size_t)B * D_MAIN * sizeof(float));
  __half* S       = (__half*)take((size_t)B * Npad * sizeof(__half));
  int*    ctxidx  = (int*)take((size_t)B * CTX * sizeof(int));
  (void)ws_size; (void)n_in; (void)out_size;

  auto packW = [&](const float* W, int K, int Nn, unsigned short* o) {
    const int total = (Nn / 16) * (K / 32) * 64;
    pack_w_kernel<<<(total + 255) / 256, 256, 0, stream>>>(W, K, Nn, o);
  };
  packW(lin_W, 32, 128, pk_lin);
  packW(e0_W1, 128, 256, pk_e0w1);
  packW(e0_W2, 256, 128, pk_e0w2);
  packW(e1_W1, 128, 256, pk_e1w1);
  packW(e1_W2, 256, 128, pk_e1w2);
  packW(K_W, 128, 128, pk_kw);

  const int encC = (N + 127) / 128;
  encode_mfma<<<encC, 256, 0, stream>>>(
      cand_x, N, pk_lin, lin_b, pk_e0w1, e0_b1, pk_e0w2, e0_b2,
      e1_g, e1_b, pk_e1w1, e1_b1, pk_e1w2, e1_b2,
      mix_g, mix_b, pk_kw, K_b, ck, cknorm, nullptr);

  const int encB = (B + 127) / 128;
  encode_mfma<<<encB, 256, 0, stream>>>(
      x_num, B, pk_lin, lin_b, pk_e0w1, e0_b1, pk_e0w2, e0_b2,
      e1_g, e1_b, pk_e1w1, e1_b1, pk_e1w2, e1_b2,
      mix_g, mix_b, pk_kw, K_b, xk, nullptr, xh);

  dim3 sg(Npad / 256, B / 64);
  score_mfma<<<sg, 256, 0, stream>>>(xk, ck, cknorm, N, Npad, S);

  topk_kernel<<<B, 256, 0, stream>>>(S, N, Npad, ctxidx);

  finalize_kernel<<<B, 256, 0, stream>>>(
      xh, xk, ck, cand_y, ctxidx,
      T_W1, T_b1, T_W2, lab_w, lab_b,
      p0_g, p0_b, p0_W1, p0_b1, p0_W2, p0_b2,
      head_g, head_b, head_W, head_bias, out);
}

// Round 3
// 689.203 us; speedup vs baseline: 2.4835x; 1.6315x over previous
//
#include <hip/hip_runtime.h>
#include <hip/hip_fp16.h>
#include <float.h>
#include <math.h>

#define D_IN 32
#define D_MAIN 128
#define D_BLOCK 256
#define CTX 96
#define LN_EPS 1e-5f

typedef short bf16x8 __attribute__((ext_vector_type(8)));
typedef float f32x4 __attribute__((ext_vector_type(4)));
typedef unsigned short ushort4v __attribute__((ext_vector_type(4)));

__device__ __forceinline__ unsigned short f2bf(float x) {
  union { float f; unsigned u; } v; v.f = x;
  const unsigned r = (v.u + 0x7FFFu + ((v.u >> 16) & 1u)) >> 16;
  return (unsigned short)r;
}

// ---------------------------------------------------------------------------
// Pack a K x N fp32 weight matrix into MFMA B-fragment order (bf16).
// ---------------------------------------------------------------------------
__global__ __launch_bounds__(256) void pack_w_kernel(
    const float* __restrict__ W, int K, int N, unsigned short* __restrict__ out)
{
  const int tid = blockIdx.x * 256 + threadIdx.x;
  const int ks = K / 32;
  const int total = (N / 16) * ks * 64;
  if (tid >= total) return;
  const int l = tid & 63, f = tid >> 6;
  const int s = f % ks, j = f / ks;
  const int kb = s * 32 + (l >> 4) * 8;
  const int n = j * 16 + (l & 15);
  unsigned short v[8];
#pragma unroll
  for (int jj = 0; jj < 8; ++jj) v[jj] = f2bf(W[(size_t)(kb + jj) * N + n]);
  ushort4v* o = (ushort4v*)(out + (size_t)tid * 8);
  ushort4v u0 = {v[0], v[1], v[2], v[3]};
  ushort4v u1 = {v[4], v[5], v[6], v[7]};
  o[0] = u0; o[1] = u1;
}

// ---------------------------------------------------------------------------
// MFMA encoder. Block = 128 rows, 4 waves.
// ---------------------------------------------------------------------------
#define LDA 136
#define LDU 72

struct EncShared {
  unsigned short As[128 * LDA];
  unsigned short Us[128 * LDU];
  float lsum[2][128];
  float lssq[2][128];
  float smu[128];
  float srs[128];
};

__device__ __forceinline__ void enc_block(
    f32x4 (&h)[4][4], EncShared& sh,
    const unsigned short* __restrict__ W1_pk, const float* __restrict__ b1,
    const unsigned short* __restrict__ W2_pk, const float* __restrict__ b2,
    int mrow, int nw, int c, int q, int lane)
{
#pragma unroll 1
  for (int ch = 0; ch < 4; ++ch) {
    f32x4 u[4][2];
#pragma unroll
    for (int mi = 0; mi < 4; ++mi)
#pragma unroll
      for (int ntl = 0; ntl < 2; ++ntl) { f32x4 z = {0.f,0.f,0.f,0.f}; u[mi][ntl] = z; }
#pragma unroll 1
    for (int s = 0; s < 4; ++s) {
      bf16x8 a[4];
#pragma unroll
      for (int mi = 0; mi < 4; ++mi)
        a[mi] = *(const bf16x8*)&sh.As[(mrow + mi*16 + c) * LDA + s*32 + q*8];
#pragma unroll
      for (int ntl = 0; ntl < 2; ++ntl) {
        const int j = ch*4 + nw*2 + ntl;
        const bf16x8 b = *(const bf16x8*)&W1_pk[((size_t)(j*4 + s) * 64 + lane) * 8];
#pragma unroll
        for (int mi = 0; mi < 4; ++mi)
          u[mi][ntl] = __builtin_amdgcn_mfma_f32_16x16x32_bf16(a[mi], b, u[mi][ntl], 0, 0, 0);
      }
    }
#pragma unroll
    for (int ntl = 0; ntl < 2; ++ntl) {
      const int colg = ch*64 + nw*32 + ntl*16 + c;
      const float bb = b1[colg];
      const int coll = nw*32 + ntl*16 + c;
#pragma unroll
      for (int mi = 0; mi < 4; ++mi)
#pragma unroll
        for (int r = 0; r < 4; ++r)
          sh.Us[(mrow + mi*16 + q*4 + r) * LDU + coll] = f2bf(fmaxf(u[mi][ntl][r] + bb, 0.f));
    }
    __syncthreads();
#pragma unroll 1
    for (int s2 = 0; s2 < 2; ++s2) {
      bf16x8 a2[4];
#pragma unroll
      for (int mi = 0; mi < 4; ++mi)
        a2[mi] = *(const bf16x8*)&sh.Us[(mrow + mi*16 + c) * LDU + s2*32 + q*8];
#pragma unroll
      for (int nt = 0; nt < 4; ++nt) {
        const int j2 = nw*4 + nt;
        const bf16x8 b = *(const bf16x8*)&W2_pk[((size_t)(j2*8 + ch*2 + s2) * 64 + lane) * 8];
#pragma unroll
        for (int mi = 0; mi < 4; ++mi)
          h[mi][nt] = __builtin_amdgcn_mfma_f32_16x16x32_bf16(a2[mi], b, h[mi][nt], 0, 0, 0);
      }
    }
    __syncthreads();
  }
#pragma unroll
  for (int nt = 0; nt < 4; ++nt) {
    const float bb = b2[nw*64 + nt*16 + c];
#pragma unroll
    for (int mi = 0; mi < 4; ++mi) {
      h[mi][nt][0] += bb; h[mi][nt][1] += bb; h[mi][nt][2] += bb; h[mi][nt][3] += bb;
    }
  }
}

__device__ __forceinline__ void enc_ln_regs(
    f32x4 (&h)[4][4], EncShared& sh,
    const float* __restrict__ g, const float* __restrict__ bv,
    int mrow, int nw, int c, int q, int t)
{
  float ps[4][4], pss[4][4];
#pragma unroll
  for (int mi = 0; mi < 4; ++mi)
#pragma unroll
    for (int r = 0; r < 4; ++r) {
      float s = 0.f, ss = 0.f;
#pragma unroll
      for (int nt = 0; nt < 4; ++nt) { const float v = h[mi][nt][r]; s += v; ss += v * v; }
      ps[mi][r] = s; pss[mi][r] = ss;
    }
#pragma unroll
  for (int off = 1; off < 16; off <<= 1) {
#pragma unroll
    for (int mi = 0; mi < 4; ++mi)
#pragma unroll
      for (int r = 0; r < 4; ++r) {
        ps[mi][r] += __shfl_xor(ps[mi][r], off, 64);
        pss[mi][r] += __shfl_xor(pss[mi][r], off, 64);
      }
  }
#pragma unroll
  for (int r = 0; r < 4; ++r) {
    if (c == r) {
#pragma unroll
      for (int mi = 0; mi < 4; ++mi) {
        const int row = mrow + mi*16 + q*4 + r;
        sh.lsum[nw][row] = ps[mi][r];
        sh.lssq[nw][row] = pss[mi][r];
      }
    }
  }
  __syncthreads();
  if (t < 128) {
    const float s = sh.lsum[0][t] + sh.lsum[1][t];
    const float ss = sh.lssq[0][t] + sh.lssq[1][t];
    const float mu = s * (1.f / 128.f);
    const float var = ss * (1.f / 128.f) - mu * mu;
    sh.smu[t] = mu;
    sh.srs[t] = rsqrtf(var + LN_EPS);
  }
  __syncthreads();
#pragma unroll
  for (int nt = 0; nt < 4; ++nt) {
    const int col = nw*64 + nt*16 + c;
    const float gg = g[col], bb = bv[col];
#pragma unroll
    for (int mi = 0; mi < 4; ++mi)
#pragma unroll
      for (int r = 0; r < 4; ++r) {
        const int row = mrow + mi*16 + q*4 + r;
        sh.As[row * LDA + col] = f2bf((h[mi][nt][r] - sh.smu[row]) * sh.srs[row] * gg + bb);
      }
  }
  __syncthreads();
}

__global__ __launch_bounds__(256, 2) void encode_mfma(
    const float* __restrict__ xin, int nrows,
    const unsigned short* __restrict__ linW_pk, const float* __restrict__ lin_b,
    const unsigned short* __restrict__ e0W1_pk, const float* __restrict__ e0_b1,
    const unsigned short* __restrict__ e0W2_pk, const float* __restrict__ e0_b2,
    const float* __restrict__ e1_g, const float* __restrict__ e1_b,
    const unsigned short* __restrict__ e1W1_pk, const float* __restrict__ e1_b1,
    const unsigned short* __restrict__ e1W2_pk, const float* __restrict__ e1_b2,
    const float* __restrict__ mix_g, const float* __restrict__ mix_b,
    const unsigned short* __restrict__ KW_pk, const float* __restrict__ K_b,
    float* __restrict__ k_out, float* __restrict__ knorm_out,
    float* __restrict__ h_out)
{
  __shared__ EncShared sh;
  const int t = threadIdx.x, lane = t & 63, w = t >> 6;
  const int mw = w & 1, nw = w >> 1;
  const int c = lane & 15, q = lane >> 4;
  const int mrow = mw * 64;
  const int row0 = blockIdx.x * 128;

  for (int i = t; i < 128 * 8; i += 256) {
    const int r = i >> 3, c4 = (i & 7) * 4;
    const int gr = row0 + r;
    float4 v = make_float4(0.f, 0.f, 0.f, 0.f);
    if (gr < nrows) v = *(const float4*)&xin[(size_t)gr * D_IN + c4];
    ushort4v u = {f2bf(v.x), f2bf(v.y), f2bf(v.z), f2bf(v.w)};
    *(ushort4v*)&sh.As[r * LDA + c4] = u;
  }
  __syncthreads();

  f32x4 h[4][4];
  {
    bf16x8 a[4];
#pragma unroll
    for (int mi = 0; mi < 4; ++mi)
      a[mi] = *(const bf16x8*)&sh.As[(mrow + mi*16 + c) * LDA + q*8];
#pragma unroll
    for (int nt = 0; nt < 4; ++nt) {
      const int j = nw*4 + nt;
      const bf16x8 b = *(const bf16x8*)&linW_pk[((size_t)j * 64 + lane) * 8];
      const float bb = lin_b[j*16 + c];
#pragma unroll
      for (int mi = 0; mi < 4; ++mi) {
        f32x4 z = {0.f, 0.f, 0.f, 0.f};
        z = __builtin_amdgcn_mfma_f32_16x16x32_bf16(a[mi], b, z, 0, 0, 0);
        z[0] += bb; z[1] += bb; z[2] += bb; z[3] += bb;
        h[mi][nt] = z;
      }
    }
  }
  __syncthreads();
#pragma unroll
  for (int nt = 0; nt < 4; ++nt)
#pragma unroll
    for (int mi = 0; mi < 4; ++mi)
#pragma unroll
      for (int r = 0; r < 4; ++r)
        sh.As[(mrow + mi*16 + q*4 + r) * LDA + nw*64 + nt*16 + c] = f2bf(h[mi][nt][r]);
  __syncthreads();

  enc_block(h, sh, e0W1_pk, e0_b1, e0W2_pk, e0_b2, mrow, nw, c, q, lane);
  enc_ln_regs(h, sh, e1_g, e1_b, mrow, nw, c, q, t);
  enc_block(h, sh, e1W1_pk, e1_b1, e1W2_pk, e1_b2, mrow, nw, c, q, lane);
  enc_ln_regs(h, sh, mix_g, mix_b, mrow, nw, c, q, t);

  f32x4 kk[4][4];
#pragma unroll
  for (int mi = 0; mi < 4; ++mi)
#pragma unroll
    for (int nt = 0; nt < 4; ++nt) { f32x4 z = {0.f,0.f,0.f,0.f}; kk[mi][nt] = z; }
#pragma unroll 1
  for (int s = 0; s < 4; ++s) {
    bf16x8 a[4];
#pragma unroll
    for (int mi = 0; mi < 4; ++mi)
      a[mi] = *(const bf16x8*)&sh.As[(mrow + mi*16 + c) * LDA + s*32 + q*8];
#pragma unroll
    for (int nt = 0; nt < 4; ++nt) {
      const int j = nw*4 + nt;
      const bf16x8 b = *(const bf16x8*)&KW_pk[((size_t)(j*4 + s) * 64 + lane) * 8];
#pragma unroll
      for (int mi = 0; mi < 4; ++mi)
        kk[mi][nt] = __builtin_amdgcn_mfma_f32_16x16x32_bf16(a[mi], b, kk[mi][nt], 0, 0, 0);
    }
  }
#pragma unroll
  for (int nt = 0; nt < 4; ++nt) {
    const int col = nw*64 + nt*16 + c;
    const float bb = K_b[col];
#pragma unroll
    for (int mi = 0; mi < 4; ++mi)
#pragma unroll
      for (int r = 0; r < 4; ++r) {
        kk[mi][nt][r] += bb;
        const int gr = row0 + mrow + mi*16 + q*4 + r;
        if (gr < nrows) k_out[(size_t)gr * D_MAIN + col] = kk[mi][nt][r];
      }
  }
  if (h_out) {
#pragma unroll
    for (int nt = 0; nt < 4; ++nt) {
      const int col = nw*64 + nt*16 + c;
#pragma unroll
      for (int mi = 0; mi < 4; ++mi)
#pragma unroll
        for (int r = 0; r < 4; ++r) {
          const int gr = row0 + mrow + mi*16 + q*4 + r;
          if (gr < nrows) h_out[(size_t)gr * D_MAIN + col] = h[mi][nt][r];
        }
    }
  }
  if (knorm_out) {
    float pss[4][4];
#pragma unroll
    for (int mi = 0; mi < 4; ++mi)
#pragma unroll
      for (int r = 0; r < 4; ++r) {
        float ss = 0.f;
#pragma unroll
        for (int nt = 0; nt < 4; ++nt) { const float v = kk[mi][nt][r]; ss += v * v; }
        pss[mi][r] = ss;
      }
#pragma unroll
    for (int off = 1; off < 16; off <<= 1)
#pragma unroll
      for (int mi = 0; mi < 4; ++mi)
#pragma unroll
        for (int r = 0; r < 4; ++r)
          pss[mi][r] += __shfl_xor(pss[mi][r], off, 64);
#pragma unroll
    for (int r = 0; r < 4; ++r) {
      if (c == r) {
#pragma unroll
        for (int mi = 0; mi < 4; ++mi)
          sh.lssq[nw][mrow + mi*16 + q*4 + r] = pss[mi][r];
      }
    }
    __syncthreads();
    if (t < 128) {
      const int gr = row0 + t;
      if (gr < nrows) knorm_out[gr] = sh.lssq[0][t] + sh.lssq[1][t];
    }
  }
}

// ---------------------------------------------------------------------------
// Score: S[b][j] = 2*dot(xk[b], ck[j]) - ||ck[j]||^2, fp16.
// Padded cols get -65504 so they can't win selection.
// ---------------------------------------------------------------------------
__global__ __launch_bounds__(256) void score_mfma(
    const float* __restrict__ xk, const float* __restrict__ ck,
    const float* __restrict__ cknorm, int N, int Npad,
    __half* __restrict__ S)
{
  __shared__ unsigned short Ks[64 * 136];
  const int t = threadIdx.x, lane = t & 63, w = t >> 6;
  const int c = lane & 15, q = lane >> 4;
  const int b0 = blockIdx.y * 64;
  const int n0 = blockIdx.x * 256 + w * 64;

  for (int i = t; i < 64 * 32; i += 256) {
    const int r = i >> 5, c4 = (i & 31) * 4;
    const float4 v = *(const float4*)&xk[(size_t)(b0 + r) * D_MAIN + c4];
    ushort4v u = {f2bf(v.x), f2bf(v.y), f2bf(v.z), f2bf(v.w)};
    *(ushort4v*)&Ks[r * 136 + c4] = u;
  }
  __syncthreads();

  f32x4 acc[4][4];
#pragma unroll
  for (int mi = 0; mi < 4; ++mi)
#pragma unroll
    for (int nt = 0; nt < 4; ++nt) { f32x4 z = {0.f,0.f,0.f,0.f}; acc[mi][nt] = z; }

#pragma unroll 1
  for (int s = 0; s < 4; ++s) {
    bf16x8 a[4];
#pragma unroll
    for (int mi = 0; mi < 4; ++mi)
      a[mi] = *(const bf16x8*)&Ks[(mi*16 + c) * 136 + s*32 + q*8];
#pragma unroll
    for (int nt = 0; nt < 4; ++nt) {
      const size_t n = (size_t)(n0 + nt*16 + c);
      const float4 v0 = *(const float4*)&ck[n * D_MAIN + s*32 + q*8];
      const float4 v1 = *(const float4*)&ck[n * D_MAIN + s*32 + q*8 + 4];
      bf16x8 b;
      b[0] = (short)f2bf(v0.x); b[1] = (short)f2bf(v0.y);
      b[2] = (short)f2bf(v0.z); b[3] = (short)f2bf(v0.w);
      b[4] = (short)f2bf(v1.x); b[5] = (short)f2bf(v1.y);
      b[6] = (short)f2bf(v1.z); b[7] = (short)f2bf(v1.w);
#pragma unroll
      for (int mi = 0; mi < 4; ++mi)
        acc[mi][nt] = __builtin_amdgcn_mfma_f32_16x16x32_bf16(a[mi], b, acc[mi][nt], 0, 0, 0);
    }
  }
#pragma unroll
  for (int nt = 0; nt < 4; ++nt) {
    const int col = n0 + nt*16 + c;
    const float cn = (col < N) ? cknorm[col] : 0.f;
#pragma unroll
    for (int mi = 0; mi < 4; ++mi)
#pragma unroll
      for (int r = 0; r < 4; ++r) {
        const int row = b0 + mi*16 + q*4 + r;
        const float sv = (col < N) ? (2.f * acc[mi][nt][r] - cn) : -65504.f;
        S[(size_t)row * Npad + col] = __float2half(sv);
      }
  }
}

// ---------------------------------------------------------------------------
// Parallel radix-threshold top-K.
// key16 = h ^ (sign ? 0xFFFF : 0x8000) is monotone; bin = key16 >> 4 (4096).
// ---------------------------------------------------------------------------
#define TK_CHUNK 4096
#define TK_RBINS 4096
#define TK_SCAP 2048

__global__ __launch_bounds__(256) void zero_int_kernel(int* __restrict__ p, int n)
{
  const int i = blockIdx.x * 256 + threadIdx.x;
  if (i < n) p[i] = 0;
}

__device__ __forceinline__ unsigned flip2(unsigned u) {
  const unsigned m = (u >> 15) & 0x00010001u;
  const unsigned xm = (m * 0xFFFFu) | ((m ^ 0x00010001u) * 0x8000u);
  return u ^ xm;
}

__global__ __launch_bounds__(256) void thist_kernel(
    const __half* __restrict__ S, int Npad, int* __restrict__ ghist)
{
  __shared__ int lh[TK_RBINS];
  const int t = threadIdx.x;
  const int row = blockIdx.y;
  const int c0 = blockIdx.x * TK_CHUNK;
  for (int i = t; i < TK_RBINS; i += 256) lh[i] = 0;
  __syncthreads();
  const unsigned* rp = (const unsigned*)(S + (size_t)row * Npad);
#pragma unroll
  for (int half = 0; half < 2; ++half) {
    const int j = c0 + half * 2048 + t * 8;   // 8 halves = uint4
    if (j < Npad) {
      const uint4 v = *(const uint4*)(rp + (j >> 1));
      const unsigned k0 = flip2(v.x), k1 = flip2(v.y);
      const unsigned k2 = flip2(v.z), k3 = flip2(v.w);
      atomicAdd(&lh[(k0 & 0xFFFFu) >> 4], 1); atomicAdd(&lh[k0 >> 20], 1);
      atomicAdd(&lh[(k1 & 0xFFFFu) >> 4], 1); atomicAdd(&lh[k1 >> 20], 1);
      atomicAdd(&lh[(k2 & 0xFFFFu) >> 4], 1); atomicAdd(&lh[k2 >> 20], 1);
      atomicAdd(&lh[(k3 & 0xFFFFu) >> 4], 1); atomicAdd(&lh[k3 >> 20], 1);
    }
  }
  __syncthreads();
  int* gh = ghist + (size_t)row * TK_RBINS;
  for (int i = t; i < TK_RBINS; i += 256) {
    const int v = lh[i];
    if (v) atomicAdd(&gh[i], v);
  }
}

__global__ __launch_bounds__(256) void tthresh_kernel(
    const int* __restrict__ ghist, int* __restrict__ thr)
{
  __shared__ int sp[257];
  const int t = threadIdx.x;
  const int row = blockIdx.x;
  const int* gh = ghist + (size_t)row * TK_RBINS;
  int s = 0;
#pragma unroll
  for (int i = 0; i < 16; ++i) s += gh[t * 16 + i];
  sp[t] = s;
  if (t == 0) sp[256] = 0;
  __syncthreads();
  // suffix scan (Hillis-Steele)
  for (int off = 1; off < 256; off <<= 1) {
    const int v = (t + off < 256) ? sp[t + off] : 0;
    __syncthreads();
    sp[t] += v;
    __syncthreads();
  }
  if (sp[t] >= CTX && (t == 255 || sp[t + 1] < CTX)) {
    // threshold group found; refine serially over its 16 bins
    int running = (t == 255) ? 0 : sp[t + 1];
    int T = t * 16;
    for (int b = t * 16 + 15; b >= t * 16; --b) {
      running += gh[b];
      if (running >= CTX) { T = b; break; }
    }
    thr[row] = T;
  }
}

__global__ __launch_bounds__(256) void tcollect_kernel(
    const __half* __restrict__ S, int Npad, const int* __restrict__ thr,
    int* __restrict__ scount, unsigned long long* __restrict__ surv)
{
  const int t = threadIdx.x;
  const int row = blockIdx.y;
  const int c0 = blockIdx.x * TK_CHUNK;
  const int T = thr[row];
  const unsigned* rp = (const unsigned*)(S + (size_t)row * Npad);
  unsigned long long* sv = surv + (size_t)row * TK_SCAP;
#pragma unroll
  for (int half = 0; half < 2; ++half) {
    const int j = c0 + half * 2048 + t * 8;
    if (j < Npad) {
      const uint4 v = *(const uint4*)(rp + (j >> 1));
      unsigned ks[4] = {flip2(v.x), flip2(v.y), flip2(v.z), flip2(v.w)};
#pragma unroll
      for (int wqi = 0; wqi < 4; ++wqi) {
        const unsigned klo = ks[wqi] & 0xFFFFu;
        const unsigned khi = ks[wqi] >> 16;
        const int jlo = j + wqi * 2, jhi = j + wqi * 2 + 1;
        if ((int)(klo >> 4) >= T) {
          const int pos = atomicAdd(&scount[row], 1);
          if (pos < TK_SCAP)
            sv[pos] = ((unsigned long long)klo << 32) | (0xFFFFFFFFu - (unsigned)jlo);
        }
        if ((int)(khi >> 4) >= T) {
          const int pos = atomicAdd(&scount[row], 1);
          if (pos < TK_SCAP)
            sv[pos] = ((unsigned long long)khi << 32) | (0xFFFFFFFFu - (unsigned)jhi);
        }
      }
    }
  }
}

__global__ __launch_bounds__(1024) void tsort_kernel(
    const unsigned long long* __restrict__ surv, const int* __restrict__ scount,
    int* __restrict__ idx_out)
{
  __shared__ unsigned long long sb[TK_SCAP];
  const int t = threadIdx.x;
  const int row = blockIdx.x;
  const int m = min(scount[row], TK_SCAP);
  const unsigned long long* sv = surv + (size_t)row * TK_SCAP;
  for (int i = t; i < TK_SCAP; i += 1024)
    sb[i] = (i < m) ? sv[i] : 0x00000000FFFFFFFFull;
  __syncthreads();
  for (int k = 2; k <= TK_SCAP; k <<= 1) {
    for (int j = k >> 1; j > 0; j >>= 1) {
      for (int i = t; i < TK_SCAP; i += 1024) {
        const int ixj = i ^ j;
        if (ixj > i) {
          const unsigned long long a = sb[i], b = sb[ixj];
          const bool desc = ((i & k) == 0);
          if ((a < b) == desc) { sb[i] = b; sb[ixj] = a; }
        }
      }
      __syncthreads();
    }
  }
  if (t < CTX)
    idx_out[row * CTX + t] = (int)(0xFFFFFFFFu - (unsigned)(sb[t] & 0xFFFFFFFFu));
}

// ---------------------------------------------------------------------------
// Finalize: exact sims + softmax, T-module, label encoder, predictor, head.
// ---------------------------------------------------------------------------
__global__ __launch_bounds__(256) void finalize_kernel(
    const float* __restrict__ xh, const float* __restrict__ xk,
    const float* __restrict__ ck, const float* __restrict__ cand_y,
    const int* __restrict__ ctx_idx,
    const float* __restrict__ T_W1, const float* __restrict__ T_b1,
    const float* __restrict__ T_W2,
    const float* __restrict__ lab_w, const float* __restrict__ lab_b,
    const float* __restrict__ p0_g, const float* __restrict__ p0_b,
    const float* __restrict__ p0_W1, const float* __restrict__ p0_b1,
    const float* __restrict__ p0_W2, const float* __restrict__ p0_b2,
    const float* __restrict__ head_g, const float* __restrict__ head_b,
    const float* __restrict__ head_W, const float* __restrict__ head_bias,
    float* __restrict__ out)
{
  const int CKP = D_MAIN + 1;
  __shared__ float ckc[CTX * (D_MAIN + 1)];
  __shared__ float kb[D_MAIN], xr[D_MAIN], accv[D_MAIN];
  __shared__ float diffs[4][D_MAIN];
  __shared__ float ubuf[4][D_BLOCK];
  __shared__ float vbuf[4][D_BLOCK];
  __shared__ float probs[CTX], ys[CTX];
  __shared__ int idxs[CTX];
  __shared__ float s_scalar[4];
  const int t = threadIdx.x;
  const int b = blockIdx.x;

  if (t < CTX) {
    const int j = ctx_idx[b * CTX + t];
    idxs[t] = j;
    ys[t] = cand_y[j];
  }
  if (t < D_MAIN) {
    kb[t] = xk[(size_t)b * D_MAIN + t];
    xr[t] = xh[(size_t)b * D_MAIN + t];
    accv[t] = 0.f;
  }
  __syncthreads();
  for (int i = t; i < CTX * D_MAIN; i += 256) {
    const int r = i >> 7, c = i & 127;
    ckc[r * CKP + c] = ck[(size_t)idxs[r] * D_MAIN + c];
  }
  __syncthreads();
  if (t < CTX) {
    float s = 0.f;
    for (int c = 0; c < D_MAIN; ++c) {
      const float d = kb[c] - ckc[t * CKP + c];
      s += d * d;
    }
    probs[t] = -s;
  }
  __syncthreads();
  if (t == 0) {
    float mval = -FLT_MAX;
    for (int i = 0; i < CTX; ++i) mval = fmaxf(mval, probs[i]);
    float sum = 0.f;
    for (int i = 0; i < CTX; ++i) {
      const float e = expf(probs[i] - mval);
      probs[i] = e;
      sum += e;
    }
    const float inv = 1.f / sum;
    float sy = 0.f;
    for (int i = 0; i < CTX; ++i) {
      probs[i] *= inv;
      sy += probs[i] * ys[i];
    }
    s_scalar[0] = sy;
  }
  __syncthreads();

  for (int jb = 0; jb < CTX; jb += 4) {
    for (int i = t; i < 4 * D_MAIN; i += 256) {
      const int jj = i >> 7, c = i & 127;
      diffs[jj][c] = kb[c] - ckc[(jb + jj) * CKP + c];
    }
    __syncthreads();
    {
      float u[4] = {0.f, 0.f, 0.f, 0.f};
      for (int c = 0; c < D_MAIN; c += 4) {
        const float w0 = T_W1[(c + 0) * D_BLOCK + t];
        const float w1 = T_W1[(c + 1) * D_BLOCK + t];
        const float w2 = T_W1[(c + 2) * D_BLOCK + t];
        const float w3 = T_W1[(c + 3) * D_BLOCK + t];
#pragma unroll
        for (int jj = 0; jj < 4; ++jj) {
          const float4 d4 = *(const float4*)&diffs[jj][c];
          u[jj] += d4.x * w0 + d4.y * w1 + d4.z * w2 + d4.w * w3;
        }
      }
      const float bb = T_b1[t];
#pragma unroll
      for (int jj = 0; jj < 4; ++jj) ubuf[jj][t] = fmaxf(u[jj] + bb, 0.f);
    }
    __syncthreads();
    {
      const int c = t & 127;
      const int d0 = (t >> 7) * 128;
      float v[4] = {0.f, 0.f, 0.f, 0.f};
      for (int d = d0; d < d0 + 128; d += 4) {
        const float w0 = T_W2[(d + 0) * D_MAIN + c];
        const float w1 = T_W2[(d + 1) * D_MAIN + c];
        const float w2 = T_W2[(d + 2) * D_MAIN + c];
        const float w3 = T_W2[(d + 3) * D_MAIN + c];
#pragma unroll
        for (int jj = 0; jj < 4; ++jj) {
          const float4 u4 = *(const float4*)&ubuf[jj][d];
          v[jj] += u4.x * w0 + u4.y * w1 + u4.z * w2 + u4.w * w3;
        }
      }
#pragma unroll
      for (int jj = 0; jj < 4; ++jj) vbuf[jj][t] = v[jj];
    }
    __syncthreads();
    if (t < D_MAIN) {
      float a = accv[t];
#pragma unroll
      for (int jj = 0; jj < 4; ++jj)
        a += probs[jb + jj] * (vbuf[jj][t] + vbuf[jj][t + 128]);
      accv[t] = a;
    }
    __syncthreads();
  }
  if (t < D_MAIN)
    xr[t] = xr[t] + accv[t] + s_scalar[0] * lab_w[t] + lab_b[t];
  __syncthreads();
  if (t == 0) {
    float s = 0.f, ss = 0.f;
    for (int c = 0; c < D_MAIN; ++c) { const float v = xr[c]; s += v; ss += v * v; }
    const float mu = s / D_MAIN;
    s_scalar[1] = mu;
    s_scalar[2] = rsqrtf(ss / D_MAIN - mu * mu + LN_EPS);
  }
  __syncthreads();
  if (t < D_MAIN)
    diffs[0][t] = (xr[t] - s_scalar[1]) * s_scalar[2] * p0_g[t] + p0_b[t];
  __syncthreads();
  {
    float u = 0.f;
    for (int c = 0; c < D_MAIN; c += 4) {
      const float w0 = p0_W1[(c + 0) * D_BLOCK + t];
      const float w1 = p0_W1[(c + 1) * D_BLOCK + t];
      const float w2 = p0_W1[(c + 2) * D_BLOCK + t];
      const float w3 = p0_W1[(c + 3) * D_BLOCK + t];
      const float4 d4 = *(const float4*)&diffs[0][c];
      u += d4.x * w0 + d4.y * w1 + d4.z * w2 + d4.w * w3;
    }
    ubuf[0][t] = fmaxf(u + p0_b1[t], 0.f);
  }
  __syncthreads();
  {
    const int c = t & 127;
    const int d0 = (t >> 7) * 128;
    float v = 0.f;
    for (int d = d0; d < d0 + 128; d += 4) {
      const float w0 = p0_W2[(d + 0) * D_MAIN + c];
      const float w1 = p0_W2[(d + 1) * D_MAIN + c];
      const float w2 = p0_W2[(d + 2) * D_MAIN + c];
      const float w3 = p0_W2[(d + 3) * D_MAIN + c];
      const float4 u4 = *(const float4*)&ubuf[0][d];
      v += u4.x * w0 + u4.y * w1 + u4.z * w2 + u4.w * w3;
    }
    vbuf[0][t] = v;
  }
  __syncthreads();
  if (t < D_MAIN) xr[t] += vbuf[0][t] + vbuf[0][t + 128] + p0_b2[t];
  __syncthreads();
  if (t == 0) {
    float s = 0.f, ss = 0.f;
    for (int c = 0; c < D_MAIN; ++c) { const float v = xr[c]; s += v; ss += v * v; }
    const float mu = s / D_MAIN;
    s_scalar[1] = mu;
    s_scalar[2] = rsqrtf(ss / D_MAIN - mu * mu + LN_EPS);
  }
  __syncthreads();
  if (t < D_MAIN) {
    float hv = (xr[t] - s_scalar[1]) * s_scalar[2] * head_g[t] + head_b[t];
    hv = fmaxf(hv, 0.f);
    diffs[0][t] = hv * head_W[t];
  }
  __syncthreads();
  if (t == 0) {
    float s = 0.f;
    for (int c = 0; c < D_MAIN; ++c) s += diffs[0][c];
    out[b] = s + head_bias[0];
  }
}

// ---------------------------------------------------------------------------
extern "C" void kernel_launch(void* const* d_in, const int* in_sizes, int n_in,
                              void* d_out, int out_size, void* d_ws, size_t ws_size,
                              hipStream_t stream)
{
  const float* x_num   = (const float*)d_in[0];
  const float* cand_x  = (const float*)d_in[1];
  const float* cand_y  = (const float*)d_in[2];
  const float* lin_W   = (const float*)d_in[4];
  const float* lin_b   = (const float*)d_in[5];
  const float* e0_W1   = (const float*)d_in[6];
  const float* e0_b1   = (const float*)d_in[7];
  const float* e0_W2   = (const float*)d_in[8];
  const float* e0_b2   = (const float*)d_in[9];
  const float* e1_g    = (const float*)d_in[10];
  const float* e1_b    = (const float*)d_in[11];
  const float* e1_W1   = (const float*)d_in[12];
  const float* e1_b1   = (const float*)d_in[13];
  const float* e1_W2   = (const float*)d_in[14];
  const float* e1_b2   = (const float*)d_in[15];
  const float* mix_g   = (const float*)d_in[16];
  const float* mix_b   = (const float*)d_in[17];
  const float* K_W     = (const float*)d_in[18];
  const float* K_b     = (const float*)d_in[19];
  const float* T_W1    = (const float*)d_in[20];
  const float* T_b1    = (const float*)d_in[21];
  const float* T_W2    = (const float*)d_in[22];
  const float* lab_w   = (const float*)d_in[23];
  const float* lab_b   = (const float*)d_in[24];
  const float* p0_g    = (const float*)d_in[25];
  const float* p0_b    = (const float*)d_in[26];
  const float* p0_W1   = (const float*)d_in[27];
  const float* p0_b1   = (const float*)d_in[28];
  const float* p0_W2   = (const float*)d_in[29];
  const float* p0_b2   = (const float*)d_in[30];
  const float* head_g  = (const float*)d_in[31];
  const float* head_b  = (const float*)d_in[32];
  const float* head_W  = (const float*)d_in[33];
  const float* head_bias = (const float*)d_in[34];
  float* out = (float*)d_out;

  const int N = in_sizes[1] / D_IN;
  const int B = in_sizes[0] / D_IN;
  const int Npad = ((N + 255) / 256) * 256;
  const int chunks = (Npad + TK_CHUNK - 1) / TK_CHUNK;

  char* p = (char*)d_ws;
  auto take = [&](size_t bytes) {
    char* q = p;
    p += (bytes + 255) & ~(size_t)255;
    return q;
  };
  unsigned short* pk_lin  = (unsigned short*)take(32  * 128 * 2);
  unsigned short* pk_e0w1 = (unsigned short*)take(128 * 256 * 2);
  unsigned short* pk_e0w2 = (unsigned short*)take(256 * 128 * 2);
  unsigned short* pk_e1w1 = (unsigned short*)take(128 * 256 * 2);
  unsigned short* pk_e1w2 = (unsigned short*)take(256 * 128 * 2);
  unsigned short* pk_kw   = (unsigned short*)take(128 * 128 * 2);
  float*  ck      = (float*)take((size_t)Npad * D_MAIN * sizeof(float));
  float*  cknorm  = (float*)take((size_t)N * sizeof(float));
  float*  xh      = (float*)take((size_t)B * D_MAIN * sizeof(float));
  float*  xk      = (float*)take((size_t)B * D_MAIN * sizeof(float));
  __half* S       = (__half*)take((size_t)B * Npad * sizeof(__half));
  int*    ctxidx  = (int*)take((size_t)B * CTX * sizeof(int));
  int*    ghist   = (int*)take((size_t)B * TK_RBINS * sizeof(int));
  int*    thr     = (int*)take((size_t)B * sizeof(int));
  int*    scount  = (int*)take((size_t)B * sizeof(int));
  unsigned long long* surv =
      (unsigned long long*)take((size_t)B * TK_SCAP * sizeof(unsigned long long));
  (void)ws_size; (void)n_in; (void)out_size;

  auto packW = [&](const float* W, int K, int Nn, unsigned short* o) {
    const int total = (Nn / 16) * (K / 32) * 64;
    pack_w_kernel<<<(total + 255) / 256, 256, 0, stream>>>(W, K, Nn, o);
  };
  packW(lin_W, 32, 128, pk_lin);
  packW(e0_W1, 128, 256, pk_e0w1);
  packW(e0_W2, 256, 128, pk_e0w2);
  packW(e1_W1, 128, 256, pk_e1w1);
  packW(e1_W2, 256, 128, pk_e1w2);
  packW(K_W, 128, 128, pk_kw);

  // zero ghist + scount (re-poisoned to 0xAA before every launch)
  {
    const int nz1 = B * TK_RBINS;
    zero_int_kernel<<<(nz1 + 255) / 256, 256, 0, stream>>>(ghist, nz1);
    zero_int_kernel<<<1, 256, 0, stream>>>(scount, B);
  }

  const int encC = (N + 127) / 128;
  encode_mfma<<<encC, 256, 0, stream>>>(
      cand_x, N, pk_lin, lin_b, pk_e0w1, e0_b1, pk_e0w2, e0_b2,
      e1_g, e1_b, pk_e1w1, e1_b1, pk_e1w2, e1_b2,
      mix_g, mix_b, pk_kw, K_b, ck, cknorm, nullptr);

  const int encB = (B + 127) / 128;
  encode_mfma<<<encB, 256, 0, stream>>>(
      x_num, B, pk_lin, lin_b, pk_e0w1, e0_b1, pk_e0w2, e0_b2,
      e1_g, e1_b, pk_e1w1, e1_b1, pk_e1w2, e1_b2,
      mix_g, mix_b, pk_kw, K_b, xk, nullptr, xh);

  dim3 sg(Npad / 256, B / 64);
  score_mfma<<<sg, 256, 0, stream>>>(xk, ck, cknorm, N, Npad, S);

  dim3 tg(chunks, B);
  thist_kernel<<<tg, 256, 0, stream>>>(S, Npad, ghist);
  tthresh_kernel<<<B, 256, 0, stream>>>(ghist, thr);
  tcollect_kernel<<<tg, 256, 0, stream>>>(S, Npad, thr, scount, surv);
  tsort_kernel<<<B, 1024, 0, stream>>>(surv, scount, ctxidx);

  finalize_kernel<<<B, 256, 0, stream>>>(
      xh, xk, ck, cand_y, ctxidx,
      T_W1, T_b1, T_W2, lab_w, lab_b,
      p0_g, p0_b, p0_W1, p0_b1, p0_W2, p0_b2,
      head_g, head_b, head_W, head_bias, out);
}

// Round 4
// 521.060 us; speedup vs baseline: 3.2849x; 1.3227x over previous
//
#include <hip/hip_runtime.h>
#include <hip/hip_fp16.h>
#include <float.h>
#include <math.h>

#define D_IN 32
#define D_MAIN 128
#define D_BLOCK 256
#define CTX 96
#define LN_EPS 1e-5f

typedef short bf16x8 __attribute__((ext_vector_type(8)));
typedef float f32x4 __attribute__((ext_vector_type(4)));
typedef unsigned short ushort4v __attribute__((ext_vector_type(4)));

__device__ __forceinline__ unsigned short f2bf(float x) {
  union { float f; unsigned u; } v; v.f = x;
  const unsigned r = (v.u + 0x7FFFu + ((v.u >> 16) & 1u)) >> 16;
  return (unsigned short)r;
}

// ---------------------------------------------------------------------------
// Pack a K x N fp32 weight matrix into MFMA B-fragment order (bf16):
// frag f = j*(K/32)+s ; lane l holds B[k=32s+(l>>4)*8+jj][n=16j+(l&15)]
// ---------------------------------------------------------------------------
__global__ __launch_bounds__(256) void pack_w_kernel(
    const float* __restrict__ W, int K, int N, unsigned short* __restrict__ out)
{
  const int tid = blockIdx.x * 256 + threadIdx.x;
  const int ks = K / 32;
  const int total = (N / 16) * ks * 64;
  if (tid >= total) return;
  const int l = tid & 63, f = tid >> 6;
  const int s = f % ks, j = f / ks;
  const int kb = s * 32 + (l >> 4) * 8;
  const int n = j * 16 + (l & 15);
  unsigned short v[8];
#pragma unroll
  for (int jj = 0; jj < 8; ++jj) v[jj] = f2bf(W[(size_t)(kb + jj) * N + n]);
  ushort4v* o = (ushort4v*)(out + (size_t)tid * 8);
  ushort4v u0 = {v[0], v[1], v[2], v[3]};
  ushort4v u1 = {v[4], v[5], v[6], v[7]};
  o[0] = u0; o[1] = u1;
}

// ---------------------------------------------------------------------------
// Shared MFMA MLP block: h (C-layout regs) += relu(As@W1+b1)@W2 [+ b2]
// As: [128][LDA] bf16, Us: [128][LDU] bf16 scratch. 4 waves (mw,nw).
// ---------------------------------------------------------------------------
#define LDA 136
#define LDU 72

__device__ __forceinline__ void mlp_block(
    f32x4 (&h)[4][4], unsigned short* __restrict__ As, unsigned short* __restrict__ Us,
    const unsigned short* __restrict__ W1_pk, const float* __restrict__ b1,
    const unsigned short* __restrict__ W2_pk, const float* __restrict__ b2,
    int mrow, int nw, int c, int q, int lane)
{
#pragma unroll 1
  for (int ch = 0; ch < 4; ++ch) {
    f32x4 u[4][2];
#pragma unroll
    for (int mi = 0; mi < 4; ++mi)
#pragma unroll
      for (int ntl = 0; ntl < 2; ++ntl) { f32x4 z = {0.f,0.f,0.f,0.f}; u[mi][ntl] = z; }
#pragma unroll 1
    for (int s = 0; s < 4; ++s) {
      bf16x8 a[4];
#pragma unroll
      for (int mi = 0; mi < 4; ++mi)
        a[mi] = *(const bf16x8*)&As[(mrow + mi*16 + c) * LDA + s*32 + q*8];
#pragma unroll
      for (int ntl = 0; ntl < 2; ++ntl) {
        const int j = ch*4 + nw*2 + ntl;
        const bf16x8 b = *(const bf16x8*)&W1_pk[((size_t)(j*4 + s) * 64 + lane) * 8];
#pragma unroll
        for (int mi = 0; mi < 4; ++mi)
          u[mi][ntl] = __builtin_amdgcn_mfma_f32_16x16x32_bf16(a[mi], b, u[mi][ntl], 0, 0, 0);
      }
    }
#pragma unroll
    for (int ntl = 0; ntl < 2; ++ntl) {
      const int colg = ch*64 + nw*32 + ntl*16 + c;
      const float bb = b1[colg];
      const int coll = nw*32 + ntl*16 + c;
#pragma unroll
      for (int mi = 0; mi < 4; ++mi)
#pragma unroll
        for (int r = 0; r < 4; ++r)
          Us[(mrow + mi*16 + q*4 + r) * LDU + coll] = f2bf(fmaxf(u[mi][ntl][r] + bb, 0.f));
    }
    __syncthreads();
#pragma unroll 1
    for (int s2 = 0; s2 < 2; ++s2) {
      bf16x8 a2[4];
#pragma unroll
      for (int mi = 0; mi < 4; ++mi)
        a2[mi] = *(const bf16x8*)&Us[(mrow + mi*16 + c) * LDU + s2*32 + q*8];
#pragma unroll
      for (int nt = 0; nt < 4; ++nt) {
        const int j2 = nw*4 + nt;
        const bf16x8 b = *(const bf16x8*)&W2_pk[((size_t)(j2*8 + ch*2 + s2) * 64 + lane) * 8];
#pragma unroll
        for (int mi = 0; mi < 4; ++mi)
          h[mi][nt] = __builtin_amdgcn_mfma_f32_16x16x32_bf16(a2[mi], b, h[mi][nt], 0, 0, 0);
      }
    }
    __syncthreads();
  }
  if (b2) {
#pragma unroll
    for (int nt = 0; nt < 4; ++nt) {
      const float bb = b2[nw*64 + nt*16 + c];
#pragma unroll
      for (int mi = 0; mi < 4; ++mi) {
        h[mi][nt][0] += bb; h[mi][nt][1] += bb; h[mi][nt][2] += bb; h[mi][nt][3] += bb;
      }
    }
  }
}

// ---------------------------------------------------------------------------
// MFMA encoder. Block = 128 rows, 4 waves.
// ---------------------------------------------------------------------------
struct EncShared {
  unsigned short As[128 * LDA];
  unsigned short Us[128 * LDU];
  float lsum[2][128];
  float lssq[2][128];
  float smu[128];
  float srs[128];
};

__device__ __forceinline__ void enc_ln_regs(
    f32x4 (&h)[4][4], EncShared& sh,
    const float* __restrict__ g, const float* __restrict__ bv,
    int mrow, int nw, int c, int q, int t)
{
  float ps[4][4], pss[4][4];
#pragma unroll
  for (int mi = 0; mi < 4; ++mi)
#pragma unroll
    for (int r = 0; r < 4; ++r) {
      float s = 0.f, ss = 0.f;
#pragma unroll
      for (int nt = 0; nt < 4; ++nt) { const float v = h[mi][nt][r]; s += v; ss += v * v; }
      ps[mi][r] = s; pss[mi][r] = ss;
    }
#pragma unroll
  for (int off = 1; off < 16; off <<= 1) {
#pragma unroll
    for (int mi = 0; mi < 4; ++mi)
#pragma unroll
      for (int r = 0; r < 4; ++r) {
        ps[mi][r] += __shfl_xor(ps[mi][r], off, 64);
        pss[mi][r] += __shfl_xor(pss[mi][r], off, 64);
      }
  }
#pragma unroll
  for (int r = 0; r < 4; ++r) {
    if (c == r) {
#pragma unroll
      for (int mi = 0; mi < 4; ++mi) {
        const int row = mrow + mi*16 + q*4 + r;
        sh.lsum[nw][row] = ps[mi][r];
        sh.lssq[nw][row] = pss[mi][r];
      }
    }
  }
  __syncthreads();
  if (t < 128) {
    const float s = sh.lsum[0][t] + sh.lsum[1][t];
    const float ss = sh.lssq[0][t] + sh.lssq[1][t];
    const float mu = s * (1.f / 128.f);
    const float var = ss * (1.f / 128.f) - mu * mu;
    sh.smu[t] = mu;
    sh.srs[t] = rsqrtf(var + LN_EPS);
  }
  __syncthreads();
#pragma unroll
  for (int nt = 0; nt < 4; ++nt) {
    const int col = nw*64 + nt*16 + c;
    const float gg = g[col], bb = bv[col];
#pragma unroll
    for (int mi = 0; mi < 4; ++mi)
#pragma unroll
      for (int r = 0; r < 4; ++r) {
        const int row = mrow + mi*16 + q*4 + r;
        sh.As[row * LDA + col] = f2bf((h[mi][nt][r] - sh.smu[row]) * sh.srs[row] * gg + bb);
      }
  }
  __syncthreads();
}

__global__ __launch_bounds__(256, 2) void encode_mfma(
    const float* __restrict__ xin, int nrows,
    const unsigned short* __restrict__ linW_pk, const float* __restrict__ lin_b,
    const unsigned short* __restrict__ e0W1_pk, const float* __restrict__ e0_b1,
    const unsigned short* __restrict__ e0W2_pk, const float* __restrict__ e0_b2,
    const float* __restrict__ e1_g, const float* __restrict__ e1_b,
    const unsigned short* __restrict__ e1W1_pk, const float* __restrict__ e1_b1,
    const unsigned short* __restrict__ e1W2_pk, const float* __restrict__ e1_b2,
    const float* __restrict__ mix_g, const float* __restrict__ mix_b,
    const unsigned short* __restrict__ KW_pk, const float* __restrict__ K_b,
    float* __restrict__ k_out, float* __restrict__ knorm_out,
    float* __restrict__ h_out)
{
  __shared__ EncShared sh;
  const int t = threadIdx.x, lane = t & 63, w = t >> 6;
  const int mw = w & 1, nw = w >> 1;
  const int c = lane & 15, q = lane >> 4;
  const int mrow = mw * 64;
  const int row0 = blockIdx.x * 128;

  for (int i = t; i < 128 * 8; i += 256) {
    const int r = i >> 3, c4 = (i & 7) * 4;
    const int gr = row0 + r;
    float4 v = make_float4(0.f, 0.f, 0.f, 0.f);
    if (gr < nrows) v = *(const float4*)&xin[(size_t)gr * D_IN + c4];
    ushort4v u = {f2bf(v.x), f2bf(v.y), f2bf(v.z), f2bf(v.w)};
    *(ushort4v*)&sh.As[r * LDA + c4] = u;
  }
  __syncthreads();

  f32x4 h[4][4];
  {
    bf16x8 a[4];
#pragma unroll
    for (int mi = 0; mi < 4; ++mi)
      a[mi] = *(const bf16x8*)&sh.As[(mrow + mi*16 + c) * LDA + q*8];
#pragma unroll
    for (int nt = 0; nt < 4; ++nt) {
      const int j = nw*4 + nt;
      const bf16x8 b = *(const bf16x8*)&linW_pk[((size_t)j * 64 + lane) * 8];
      const float bb = lin_b[j*16 + c];
#pragma unroll
      for (int mi = 0; mi < 4; ++mi) {
        f32x4 z = {0.f, 0.f, 0.f, 0.f};
        z = __builtin_amdgcn_mfma_f32_16x16x32_bf16(a[mi], b, z, 0, 0, 0);
        z[0] += bb; z[1] += bb; z[2] += bb; z[3] += bb;
        h[mi][nt] = z;
      }
    }
  }
  __syncthreads();
#pragma unroll
  for (int nt = 0; nt < 4; ++nt)
#pragma unroll
    for (int mi = 0; mi < 4; ++mi)
#pragma unroll
      for (int r = 0; r < 4; ++r)
        sh.As[(mrow + mi*16 + q*4 + r) * LDA + nw*64 + nt*16 + c] = f2bf(h[mi][nt][r]);
  __syncthreads();

  mlp_block(h, sh.As, sh.Us, e0W1_pk, e0_b1, e0W2_pk, e0_b2, mrow, nw, c, q, lane);
  enc_ln_regs(h, sh, e1_g, e1_b, mrow, nw, c, q, t);
  mlp_block(h, sh.As, sh.Us, e1W1_pk, e1_b1, e1W2_pk, e1_b2, mrow, nw, c, q, lane);
  enc_ln_regs(h, sh, mix_g, mix_b, mrow, nw, c, q, t);

  f32x4 kk[4][4];
#pragma unroll
  for (int mi = 0; mi < 4; ++mi)
#pragma unroll
    for (int nt = 0; nt < 4; ++nt) { f32x4 z = {0.f,0.f,0.f,0.f}; kk[mi][nt] = z; }
#pragma unroll 1
  for (int s = 0; s < 4; ++s) {
    bf16x8 a[4];
#pragma unroll
    for (int mi = 0; mi < 4; ++mi)
      a[mi] = *(const bf16x8*)&sh.As[(mrow + mi*16 + c) * LDA + s*32 + q*8];
#pragma unroll
    for (int nt = 0; nt < 4; ++nt) {
      const int j = nw*4 + nt;
      const bf16x8 b = *(const bf16x8*)&KW_pk[((size_t)(j*4 + s) * 64 + lane) * 8];
#pragma unroll
      for (int mi = 0; mi < 4; ++mi)
        kk[mi][nt] = __builtin_amdgcn_mfma_f32_16x16x32_bf16(a[mi], b, kk[mi][nt], 0, 0, 0);
    }
  }
#pragma unroll
  for (int nt = 0; nt < 4; ++nt) {
    const int col = nw*64 + nt*16 + c;
    const float bb = K_b[col];
#pragma unroll
    for (int mi = 0; mi < 4; ++mi)
#pragma unroll
      for (int r = 0; r < 4; ++r) {
        kk[mi][nt][r] += bb;
        const int gr = row0 + mrow + mi*16 + q*4 + r;
        if (gr < nrows) k_out[(size_t)gr * D_MAIN + col] = kk[mi][nt][r];
      }
  }
  if (h_out) {
#pragma unroll
    for (int nt = 0; nt < 4; ++nt) {
      const int col = nw*64 + nt*16 + c;
#pragma unroll
      for (int mi = 0; mi < 4; ++mi)
#pragma unroll
        for (int r = 0; r < 4; ++r) {
          const int gr = row0 + mrow + mi*16 + q*4 + r;
          if (gr < nrows) h_out[(size_t)gr * D_MAIN + col] = h[mi][nt][r];
        }
    }
  }
  if (knorm_out) {
    float pss[4][4];
#pragma unroll
    for (int mi = 0; mi < 4; ++mi)
#pragma unroll
      for (int r = 0; r < 4; ++r) {
        float ss = 0.f;
#pragma unroll
        for (int nt = 0; nt < 4; ++nt) { const float v = kk[mi][nt][r]; ss += v * v; }
        pss[mi][r] = ss;
      }
#pragma unroll
    for (int off = 1; off < 16; off <<= 1)
#pragma unroll
      for (int mi = 0; mi < 4; ++mi)
#pragma unroll
        for (int r = 0; r < 4; ++r)
          pss[mi][r] += __shfl_xor(pss[mi][r], off, 64);
#pragma unroll
    for (int r = 0; r < 4; ++r) {
      if (c == r) {
#pragma unroll
        for (int mi = 0; mi < 4; ++mi)
          sh.lssq[nw][mrow + mi*16 + q*4 + r] = pss[mi][r];
      }
    }
    __syncthreads();
    if (t < 128) {
      const int gr = row0 + t;
      if (gr < nrows) knorm_out[gr] = sh.lssq[0][t] + sh.lssq[1][t];
    }
  }
}

// ---------------------------------------------------------------------------
// Score: S[b][j] = 2*dot(xk[b], ck[j]) - ||ck[j]||^2, fp16.
// ---------------------------------------------------------------------------
__global__ __launch_bounds__(256) void score_mfma(
    const float* __restrict__ xk, const float* __restrict__ ck,
    const float* __restrict__ cknorm, int N, int Npad,
    __half* __restrict__ S)
{
  __shared__ unsigned short Ks[64 * 136];
  const int t = threadIdx.x, lane = t & 63, w = t >> 6;
  const int c = lane & 15, q = lane >> 4;
  const int b0 = blockIdx.y * 64;
  const int n0 = blockIdx.x * 256 + w * 64;

  for (int i = t; i < 64 * 32; i += 256) {
    const int r = i >> 5, c4 = (i & 31) * 4;
    const float4 v = *(const float4*)&xk[(size_t)(b0 + r) * D_MAIN + c4];
    ushort4v u = {f2bf(v.x), f2bf(v.y), f2bf(v.z), f2bf(v.w)};
    *(ushort4v*)&Ks[r * 136 + c4] = u;
  }
  __syncthreads();

  f32x4 acc[4][4];
#pragma unroll
  for (int mi = 0; mi < 4; ++mi)
#pragma unroll
    for (int nt = 0; nt < 4; ++nt) { f32x4 z = {0.f,0.f,0.f,0.f}; acc[mi][nt] = z; }

#pragma unroll 1
  for (int s = 0; s < 4; ++s) {
    bf16x8 a[4];
#pragma unroll
    for (int mi = 0; mi < 4; ++mi)
      a[mi] = *(const bf16x8*)&Ks[(mi*16 + c) * 136 + s*32 + q*8];
#pragma unroll
    for (int nt = 0; nt < 4; ++nt) {
      const size_t n = (size_t)(n0 + nt*16 + c);
      const float4 v0 = *(const float4*)&ck[n * D_MAIN + s*32 + q*8];
      const float4 v1 = *(const float4*)&ck[n * D_MAIN + s*32 + q*8 + 4];
      bf16x8 b;
      b[0] = (short)f2bf(v0.x); b[1] = (short)f2bf(v0.y);
      b[2] = (short)f2bf(v0.z); b[3] = (short)f2bf(v0.w);
      b[4] = (short)f2bf(v1.x); b[5] = (short)f2bf(v1.y);
      b[6] = (short)f2bf(v1.z); b[7] = (short)f2bf(v1.w);
#pragma unroll
      for (int mi = 0; mi < 4; ++mi)
        acc[mi][nt] = __builtin_amdgcn_mfma_f32_16x16x32_bf16(a[mi], b, acc[mi][nt], 0, 0, 0);
    }
  }
#pragma unroll
  for (int nt = 0; nt < 4; ++nt) {
    const int col = n0 + nt*16 + c;
    const float cn = (col < N) ? cknorm[col] : 0.f;
#pragma unroll
    for (int mi = 0; mi < 4; ++mi)
#pragma unroll
      for (int r = 0; r < 4; ++r) {
        const int row = b0 + mi*16 + q*4 + r;
        const float sv = (col < N) ? (2.f * acc[mi][nt][r] - cn) : -65504.f;
        S[(size_t)row * Npad + col] = __float2half(sv);
      }
  }
}

// ---------------------------------------------------------------------------
// Parallel radix-threshold top-K.
// ---------------------------------------------------------------------------
#define TK_CHUNK 4096
#define TK_RBINS 4096
#define TK_SCAP 2048

__global__ __launch_bounds__(256) void zero_int_kernel(int* __restrict__ p, int n)
{
  const int i = blockIdx.x * 256 + threadIdx.x;
  if (i < n) p[i] = 0;
}

__device__ __forceinline__ unsigned flip2(unsigned u) {
  const unsigned m = (u >> 15) & 0x00010001u;
  const unsigned xm = (m * 0xFFFFu) | ((m ^ 0x00010001u) * 0x8000u);
  return u ^ xm;
}

__global__ __launch_bounds__(256) void thist_kernel(
    const __half* __restrict__ S, int Npad, int* __restrict__ ghist)
{
  __shared__ int lh[TK_RBINS];
  const int t = threadIdx.x;
  const int row = blockIdx.y;
  const int c0 = blockIdx.x * TK_CHUNK;
  for (int i = t; i < TK_RBINS; i += 256) lh[i] = 0;
  __syncthreads();
  const unsigned* rp = (const unsigned*)(S + (size_t)row * Npad);
#pragma unroll
  for (int half = 0; half < 2; ++half) {
    const int j = c0 + half * 2048 + t * 8;
    if (j < Npad) {
      const uint4 v = *(const uint4*)(rp + (j >> 1));
      const unsigned k0 = flip2(v.x), k1 = flip2(v.y);
      const unsigned k2 = flip2(v.z), k3 = flip2(v.w);
      atomicAdd(&lh[(k0 & 0xFFFFu) >> 4], 1); atomicAdd(&lh[k0 >> 20], 1);
      atomicAdd(&lh[(k1 & 0xFFFFu) >> 4], 1); atomicAdd(&lh[k1 >> 20], 1);
      atomicAdd(&lh[(k2 & 0xFFFFu) >> 4], 1); atomicAdd(&lh[k2 >> 20], 1);
      atomicAdd(&lh[(k3 & 0xFFFFu) >> 4], 1); atomicAdd(&lh[k3 >> 20], 1);
    }
  }
  __syncthreads();
  int* gh = ghist + (size_t)row * TK_RBINS;
  for (int i = t; i < TK_RBINS; i += 256) {
    const int v = lh[i];
    if (v) atomicAdd(&gh[i], v);
  }
}

__global__ __launch_bounds__(256) void tthresh_kernel(
    const int* __restrict__ ghist, int* __restrict__ thr)
{
  __shared__ int sp[257];
  const int t = threadIdx.x;
  const int row = blockIdx.x;
  const int* gh = ghist + (size_t)row * TK_RBINS;
  int s = 0;
#pragma unroll
  for (int i = 0; i < 16; ++i) s += gh[t * 16 + i];
  sp[t] = s;
  if (t == 0) sp[256] = 0;
  __syncthreads();
  for (int off = 1; off < 256; off <<= 1) {
    const int v = (t + off < 256) ? sp[t + off] : 0;
    __syncthreads();
    sp[t] += v;
    __syncthreads();
  }
  if (sp[t] >= CTX && (t == 255 || sp[t + 1] < CTX)) {
    int running = (t == 255) ? 0 : sp[t + 1];
    int T = t * 16;
    for (int b = t * 16 + 15; b >= t * 16; --b) {
      running += gh[b];
      if (running >= CTX) { T = b; break; }
    }
    thr[row] = T;
  }
}

__global__ __launch_bounds__(256) void tcollect_kernel(
    const __half* __restrict__ S, int Npad, const int* __restrict__ thr,
    int* __restrict__ scount, unsigned long long* __restrict__ surv)
{
  const int t = threadIdx.x;
  const int row = blockIdx.y;
  const int c0 = blockIdx.x * TK_CHUNK;
  const int T = thr[row];
  const unsigned* rp = (const unsigned*)(S + (size_t)row * Npad);
  unsigned long long* sv = surv + (size_t)row * TK_SCAP;
#pragma unroll
  for (int half = 0; half < 2; ++half) {
    const int j = c0 + half * 2048 + t * 8;
    if (j < Npad) {
      const uint4 v = *(const uint4*)(rp + (j >> 1));
      unsigned ks[4] = {flip2(v.x), flip2(v.y), flip2(v.z), flip2(v.w)};
#pragma unroll
      for (int wqi = 0; wqi < 4; ++wqi) {
        const unsigned klo = ks[wqi] & 0xFFFFu;
        const unsigned khi = ks[wqi] >> 16;
        const int jlo = j + wqi * 2, jhi = j + wqi * 2 + 1;
        if ((int)(klo >> 4) >= T) {
          const int pos = atomicAdd(&scount[row], 1);
          if (pos < TK_SCAP)
            sv[pos] = ((unsigned long long)klo << 32) | (0xFFFFFFFFu - (unsigned)jlo);
        }
        if ((int)(khi >> 4) >= T) {
          const int pos = atomicAdd(&scount[row], 1);
          if (pos < TK_SCAP)
            sv[pos] = ((unsigned long long)khi << 32) | (0xFFFFFFFFu - (unsigned)jhi);
        }
      }
    }
  }
}

__global__ __launch_bounds__(1024) void tsort_kernel(
    const unsigned long long* __restrict__ surv, const int* __restrict__ scount,
    int* __restrict__ idx_out)
{
  __shared__ unsigned long long sb[TK_SCAP];
  const int t = threadIdx.x;
  const int row = blockIdx.x;
  const int m = min(scount[row], TK_SCAP);
  const unsigned long long* sv = surv + (size_t)row * TK_SCAP;
  for (int i = t; i < TK_SCAP; i += 1024)
    sb[i] = (i < m) ? sv[i] : 0x00000000FFFFFFFFull;
  __syncthreads();
  for (int k = 2; k <= TK_SCAP; k <<= 1) {
    for (int j = k >> 1; j > 0; j >>= 1) {
      for (int i = t; i < TK_SCAP; i += 1024) {
        const int ixj = i ^ j;
        if (ixj > i) {
          const unsigned long long a = sb[i], b = sb[ixj];
          const bool desc = ((i & k) == 0);
          if ((a < b) == desc) { sb[i] = b; sb[ixj] = a; }
        }
      }
      __syncthreads();
    }
  }
  if (t < CTX)
    idx_out[row * CTX + t] = (int)(0xFFFFFFFFu - (unsigned)(sb[t] & 0xFFFFFFFFu));
}

// ---------------------------------------------------------------------------
// T-module + predictor + head, MFMA. One block per query row, 4 waves.
// Rows of the MFMA M-dim = 96 neighbors (pad to 128 with zeros, probs=0).
// ---------------------------------------------------------------------------
struct TmodShared {
  unsigned short As[128 * LDA];   // diff rows, bf16
  unsigned short Us[128 * LDU];   // relu scratch (spart overlays this)
  float part[2][128];
  float probs[128];
  float sims[128];
  float kb[128];
  float xhs[128];
  float ys[128];
  int   idxs[128];
  float ubuf[256];
  float vbuf[256];
  float xr[128];
  float dl[128];
  float scal[4];
};

__global__ __launch_bounds__(256, 2) void tmod_kernel(
    const float* __restrict__ xh, const float* __restrict__ xk,
    const float* __restrict__ ck, const float* __restrict__ cand_y,
    const int* __restrict__ ctx_idx,
    const unsigned short* __restrict__ TW1_pk, const float* __restrict__ T_b1,
    const unsigned short* __restrict__ TW2_pk,
    const float* __restrict__ lab_w, const float* __restrict__ lab_b,
    const float* __restrict__ p0_g, const float* __restrict__ p0_b,
    const float* __restrict__ p0_W1, const float* __restrict__ p0_b1,
    const float* __restrict__ p0_W2, const float* __restrict__ p0_b2,
    const float* __restrict__ head_g, const float* __restrict__ head_b,
    const float* __restrict__ head_W, const float* __restrict__ head_bias,
    float* __restrict__ out)
{
  __shared__ TmodShared sh;
  const int t = threadIdx.x, lane = t & 63, w = t >> 6;
  const int mw = w & 1, nw = w >> 1;
  const int c = lane & 15, q = lane >> 4;
  const int mrow = mw * 64;
  const int b = blockIdx.x;
  float* spart = (float*)sh.Us;   // [128][16], overlays Us (used pre-GEMM only)

  if (t < 128) {
    sh.ys[t] = 0.f;
    if (t < CTX) {
      const int j = ctx_idx[b * CTX + t];
      sh.idxs[t] = j;
      sh.ys[t] = cand_y[j];
    }
  }
  if (t < 32) {
    *(float4*)&sh.kb[t * 4] = *(const float4*)&xk[(size_t)b * D_MAIN + t * 4];
  } else if (t < 64) {
    const int i = t - 32;
    *(float4*)&sh.xhs[i * 4] = *(const float4*)&xh[(size_t)b * D_MAIN + i * 4];
  }
  __syncthreads();

  // stage diffs: row r (<96): diff = kb - ck[idx[r]]; bf16 into As; ss -> spart
  for (int i = t; i < 128 * 16; i += 256) {
    const int r = i >> 4, seg = i & 15, c0 = seg * 8;
    if (r < CTX) {
      const float* cr = &ck[(size_t)sh.idxs[r] * D_MAIN + c0];
      const float4 v0 = *(const float4*)cr;
      const float4 v1 = *(const float4*)(cr + 4);
      const float4 k0 = *(const float4*)&sh.kb[c0];
      const float4 k1 = *(const float4*)&sh.kb[c0 + 4];
      const float d0 = k0.x - v0.x, d1 = k0.y - v0.y, d2 = k0.z - v0.z, d3 = k0.w - v0.w;
      const float d4 = k1.x - v1.x, d5 = k1.y - v1.y, d6 = k1.z - v1.z, d7 = k1.w - v1.w;
      ushort4v u0 = {f2bf(d0), f2bf(d1), f2bf(d2), f2bf(d3)};
      ushort4v u1 = {f2bf(d4), f2bf(d5), f2bf(d6), f2bf(d7)};
      *(ushort4v*)&sh.As[r * LDA + c0] = u0;
      *(ushort4v*)&sh.As[r * LDA + c0 + 4] = u1;
      spart[r * 16 + seg] = d0*d0 + d1*d1 + d2*d2 + d3*d3 + d4*d4 + d5*d5 + d6*d6 + d7*d7;
    } else {
      ushort4v z = {0, 0, 0, 0};
      *(ushort4v*)&sh.As[r * LDA + c0] = z;
      *(ushort4v*)&sh.As[r * LDA + c0 + 4] = z;
    }
  }
  __syncthreads();
  if (t < 128) {
    float s = 0.f;
    if (t < CTX) {
#pragma unroll
      for (int seg = 0; seg < 16; ++seg) s += spart[t * 16 + seg];
      sh.sims[t] = -s;
    } else {
      sh.sims[t] = -FLT_MAX;
    }
  }
  __syncthreads();
  // softmax (parallel): max
  if (t < 64) {
    float m = fmaxf(sh.sims[t], sh.sims[t + 64]);
#pragma unroll
    for (int off = 32; off > 0; off >>= 1) m = fmaxf(m, __shfl_xor(m, off, 64));
    if (t == 0) sh.scal[0] = m;
  }
  __syncthreads();
  if (t < 128) {
    const float e = (t < CTX) ? __expf(sh.sims[t] - sh.scal[0]) : 0.f;
    sh.probs[t] = e;
  }
  __syncthreads();
  if (t < 64) {
    float s = sh.probs[t] + sh.probs[t + 64];
#pragma unroll
    for (int off = 32; off > 0; off >>= 1) s += __shfl_xor(s, off, 64);
    if (t == 0) sh.scal[1] = 1.f / s;
  }
  __syncthreads();
  if (t < 128) sh.probs[t] *= sh.scal[1];
  __syncthreads();
  if (t < 64) {
    float sy = sh.probs[t] * sh.ys[t] + sh.probs[t + 64] * sh.ys[t + 64];
#pragma unroll
    for (int off = 32; off > 0; off >>= 1) sy += __shfl_xor(sy, off, 64);
    if (t == 0) sh.scal[2] = sy;
  }
  __syncthreads();   // spart (Us) reads done; mlp_block may now write Us

  // T-module MFMA: h = relu(diff @ T_W1 + b1) @ T_W2
  f32x4 h[4][4];
#pragma unroll
  for (int mi = 0; mi < 4; ++mi)
#pragma unroll
    for (int nt = 0; nt < 4; ++nt) { f32x4 z = {0.f,0.f,0.f,0.f}; h[mi][nt] = z; }
  mlp_block(h, sh.As, sh.Us, TW1_pk, T_b1, TW2_pk, nullptr, mrow, nw, c, q, lane);

  // weighted column reduction: ctx[col] = sum_rows probs[row] * h[row][col]
#pragma unroll
  for (int nt = 0; nt < 4; ++nt) {
    float p = 0.f;
#pragma unroll
    for (int mi = 0; mi < 4; ++mi)
#pragma unroll
      for (int r = 0; r < 4; ++r)
        p += sh.probs[mrow + mi*16 + q*4 + r] * h[mi][nt][r];
    p += __shfl_xor(p, 16, 64);
    p += __shfl_xor(p, 32, 64);
    if (q == 0) sh.part[mw][nw*64 + nt*16 + c] = p;
  }
  __syncthreads();

  // x = xh + ctx + sy*lab_w + lab_b
  if (t < 128)
    sh.xr[t] = sh.xhs[t] + sh.part[0][t] + sh.part[1][t] + sh.scal[2] * lab_w[t] + lab_b[t];
  __syncthreads();
  // predictor prenorm LN (parallel)
  if (t < 64) {
    float s = sh.xr[t] + sh.xr[t + 64];
    float ss = sh.xr[t]*sh.xr[t] + sh.xr[t+64]*sh.xr[t+64];
#pragma unroll
    for (int off = 32; off > 0; off >>= 1) {
      s += __shfl_xor(s, off, 64);
      ss += __shfl_xor(ss, off, 64);
    }
    if (t == 0) {
      const float mu = s * (1.f / 128.f);
      sh.scal[0] = mu;
      sh.scal[1] = rsqrtf(ss * (1.f / 128.f) - mu * mu + LN_EPS);
    }
  }
  __syncthreads();
  if (t < 128)
    sh.dl[t] = (sh.xr[t] - sh.scal[0]) * sh.scal[1] * p0_g[t] + p0_b[t];
  __syncthreads();
  {
    float u = 0.f;
    for (int cc = 0; cc < D_MAIN; cc += 4) {
      const float w0 = p0_W1[(cc + 0) * D_BLOCK + t];
      const float w1 = p0_W1[(cc + 1) * D_BLOCK + t];
      const float w2 = p0_W1[(cc + 2) * D_BLOCK + t];
      const float w3 = p0_W1[(cc + 3) * D_BLOCK + t];
      const float4 d4 = *(const float4*)&sh.dl[cc];
      u += d4.x * w0 + d4.y * w1 + d4.z * w2 + d4.w * w3;
    }
    sh.ubuf[t] = fmaxf(u + p0_b1[t], 0.f);
  }
  __syncthreads();
  {
    const int cc = t & 127;
    const int d0 = (t >> 7) * 128;
    float v = 0.f;
    for (int d = d0; d < d0 + 128; d += 4) {
      const float w0 = p0_W2[(d + 0) * D_MAIN + cc];
      const float w1 = p0_W2[(d + 1) * D_MAIN + cc];
      const float w2 = p0_W2[(d + 2) * D_MAIN + cc];
      const float w3 = p0_W2[(d + 3) * D_MAIN + cc];
      const float4 u4 = *(const float4*)&sh.ubuf[d];
      v += u4.x * w0 + u4.y * w1 + u4.z * w2 + u4.w * w3;
    }
    sh.vbuf[t] = v;
  }
  __syncthreads();
  if (t < 128) sh.xr[t] += sh.vbuf[t] + sh.vbuf[t + 128] + p0_b2[t];
  __syncthreads();
  // head LN (parallel) -> relu -> dot
  if (t < 64) {
    float s = sh.xr[t] + sh.xr[t + 64];
    float ss = sh.xr[t]*sh.xr[t] + sh.xr[t+64]*sh.xr[t+64];
#pragma unroll
    for (int off = 32; off > 0; off >>= 1) {
      s += __shfl_xor(s, off, 64);
      ss += __shfl_xor(ss, off, 64);
    }
    if (t == 0) {
      const float mu = s * (1.f / 128.f);
      sh.scal[0] = mu;
      sh.scal[1] = rsqrtf(ss * (1.f / 128.f) - mu * mu + LN_EPS);
    }
  }
  __syncthreads();
  if (t < 128) {
    float hv = (sh.xr[t] - sh.scal[0]) * sh.scal[1] * head_g[t] + head_b[t];
    sh.dl[t] = fmaxf(hv, 0.f) * head_W[t];
  }
  __syncthreads();
  if (t < 64) {
    float s = sh.dl[t] + sh.dl[t + 64];
#pragma unroll
    for (int off = 32; off > 0; off >>= 1) s += __shfl_xor(s, off, 64);
    if (t == 0) out[b] = s + head_bias[0];
  }
}

// ---------------------------------------------------------------------------
extern "C" void kernel_launch(void* const* d_in, const int* in_sizes, int n_in,
                              void* d_out, int out_size, void* d_ws, size_t ws_size,
                              hipStream_t stream)
{
  const float* x_num   = (const float*)d_in[0];
  const float* cand_x  = (const float*)d_in[1];
  const float* cand_y  = (const float*)d_in[2];
  const float* lin_W   = (const float*)d_in[4];
  const float* lin_b   = (const float*)d_in[5];
  const float* e0_W1   = (const float*)d_in[6];
  const float* e0_b1   = (const float*)d_in[7];
  const float* e0_W2   = (const float*)d_in[8];
  const float* e0_b2   = (const float*)d_in[9];
  const float* e1_g    = (const float*)d_in[10];
  const float* e1_b    = (const float*)d_in[11];
  const float* e1_W1   = (const float*)d_in[12];
  const float* e1_b1   = (const float*)d_in[13];
  const float* e1_W2   = (const float*)d_in[14];
  const float* e1_b2   = (const float*)d_in[15];
  const float* mix_g   = (const float*)d_in[16];
  const float* mix_b   = (const float*)d_in[17];
  const float* K_W     = (const float*)d_in[18];
  const float* K_b     = (const float*)d_in[19];
  const float* T_W1    = (const float*)d_in[20];
  const float* T_b1    = (const float*)d_in[21];
  const float* T_W2    = (const float*)d_in[22];
  const float* lab_w   = (const float*)d_in[23];
  const float* lab_b   = (const float*)d_in[24];
  const float* p0_g    = (const float*)d_in[25];
  const float* p0_b    = (const float*)d_in[26];
  const float* p0_W1   = (const float*)d_in[27];
  const float* p0_b1   = (const float*)d_in[28];
  const float* p0_W2   = (const float*)d_in[29];
  const float* p0_b2   = (const float*)d_in[30];
  const float* head_g  = (const float*)d_in[31];
  const float* head_b  = (const float*)d_in[32];
  const float* head_W  = (const float*)d_in[33];
  const float* head_bias = (const float*)d_in[34];
  float* out = (float*)d_out;

  const int N = in_sizes[1] / D_IN;
  const int B = in_sizes[0] / D_IN;
  const int Npad = ((N + 255) / 256) * 256;
  const int chunks = (Npad + TK_CHUNK - 1) / TK_CHUNK;

  char* p = (char*)d_ws;
  auto take = [&](size_t bytes) {
    char* q = p;
    p += (bytes + 255) & ~(size_t)255;
    return q;
  };
  unsigned short* pk_lin  = (unsigned short*)take(32  * 128 * 2);
  unsigned short* pk_e0w1 = (unsigned short*)take(128 * 256 * 2);
  unsigned short* pk_e0w2 = (unsigned short*)take(256 * 128 * 2);
  unsigned short* pk_e1w1 = (unsigned short*)take(128 * 256 * 2);
  unsigned short* pk_e1w2 = (unsigned short*)take(256 * 128 * 2);
  unsigned short* pk_kw   = (unsigned short*)take(128 * 128 * 2);
  unsigned short* pk_tw1  = (unsigned short*)take(128 * 256 * 2);
  unsigned short* pk_tw2  = (unsigned short*)take(256 * 128 * 2);
  float*  ck      = (float*)take((size_t)Npad * D_MAIN * sizeof(float));
  float*  cknorm  = (float*)take((size_t)N * sizeof(float));
  float*  xh      = (float*)take((size_t)B * D_MAIN * sizeof(float));
  float*  xk      = (float*)take((size_t)B * D_MAIN * sizeof(float));
  __half* S       = (__half*)take((size_t)B * Npad * sizeof(__half));
  int*    ctxidx  = (int*)take((size_t)B * CTX * sizeof(int));
  int*    ghist   = (int*)take((size_t)B * TK_RBINS * sizeof(int));
  int*    thr     = (int*)take((size_t)B * sizeof(int));
  int*    scount  = (int*)take((size_t)B * sizeof(int));
  unsigned long long* surv =
      (unsigned long long*)take((size_t)B * TK_SCAP * sizeof(unsigned long long));
  (void)ws_size; (void)n_in; (void)out_size;

  auto packW = [&](const float* W, int K, int Nn, unsigned short* o) {
    const int total = (Nn / 16) * (K / 32) * 64;
    pack_w_kernel<<<(total + 255) / 256, 256, 0, stream>>>(W, K, Nn, o);
  };
  packW(lin_W, 32, 128, pk_lin);
  packW(e0_W1, 128, 256, pk_e0w1);
  packW(e0_W2, 256, 128, pk_e0w2);
  packW(e1_W1, 128, 256, pk_e1w1);
  packW(e1_W2, 256, 128, pk_e1w2);
  packW(K_W, 128, 128, pk_kw);
  packW(T_W1, 128, 256, pk_tw1);
  packW(T_W2, 256, 128, pk_tw2);

  {
    const int nz1 = B * TK_RBINS;
    zero_int_kernel<<<(nz1 + 255) / 256, 256, 0, stream>>>(ghist, nz1);
    zero_int_kernel<<<1, 256, 0, stream>>>(scount, B);
  }

  const int encC = (N + 127) / 128;
  encode_mfma<<<encC, 256, 0, stream>>>(
      cand_x, N, pk_lin, lin_b, pk_e0w1, e0_b1, pk_e0w2, e0_b2,
      e1_g, e1_b, pk_e1w1, e1_b1, pk_e1w2, e1_b2,
      mix_g, mix_b, pk_kw, K_b, ck, cknorm, nullptr);

  const int encB = (B + 127) / 128;
  encode_mfma<<<encB, 256, 0, stream>>>(
      x_num, B, pk_lin, lin_b, pk_e0w1, e0_b1, pk_e0w2, e0_b2,
      e1_g, e1_b, pk_e1w1, e1_b1, pk_e1w2, e1_b2,
      mix_g, mix_b, pk_kw, K_b, xk, nullptr, xh);

  dim3 sg(Npad / 256, B / 64);
  score_mfma<<<sg, 256, 0, stream>>>(xk, ck, cknorm, N, Npad, S);

  dim3 tg(chunks, B);
  thist_kernel<<<tg, 256, 0, stream>>>(S, Npad, ghist);
  tthresh_kernel<<<B, 256, 0, stream>>>(ghist, thr);
  tcollect_kernel<<<tg, 256, 0, stream>>>(S, Npad, thr, scount, surv);
  tsort_kernel<<<B, 1024, 0, stream>>>(surv, scount, ctxidx);

  tmod_kernel<<<B, 256, 0, stream>>>(
      xh, xk, ck, cand_y, ctxidx,
      pk_tw1, T_b1, pk_tw2, lab_w, lab_b,
      p0_g, p0_b, p0_W1, p0_b1, p0_W2, p0_b2,
      head_g, head_b, head_W, head_bias, out);
}